// Round 10
// baseline (301.437 us; speedup 1.0000x reference)
//
#include <hip/hip_runtime.h>

#define CAP 64
#define BCAP 6144   // per-bucket edge capacity (mean 4352 + 27 sigma)

typedef _Float16 h8 __attribute__((ext_vector_type(8)));
typedef _Float16 h4 __attribute__((ext_vector_type(4)));
typedef _Float16 h2 __attribute__((ext_vector_type(2)));
typedef float f32x4 __attribute__((ext_vector_type(4)));

__device__ __forceinline__ uint4 pack8(float4 a, float4 b){
  union { h8 h; uint4 u; } cv;
  cv.h = (h8){ (_Float16)a.x, (_Float16)a.y, (_Float16)a.z, (_Float16)a.w,
               (_Float16)b.x, (_Float16)b.y, (_Float16)b.z, (_Float16)b.w };
  return cv.u;
}

// packed-f16 logit partial: sum_k dot2(lrelu(c2k + xr2k), att2k), f32 accum
__device__ __forceinline__ float edge_logit(uint4 xu, const h2* xrh, const h2* avh){
  union { uint4 u; h2 v[4]; } cu; cu.u = xu;
  const h2 z2 = { (_Float16)0.f, (_Float16)0.f };
  const h2 sl = { (_Float16)0.2f, (_Float16)0.2f };
  float p = 0.f;
  #pragma unroll
  for (int k = 0; k < 4; ++k){
    h2 t  = cu.v[k] + xrh[k];
    h2 hi = __builtin_elementwise_max(t, z2);
    h2 lo = __builtin_elementwise_min(t, z2);
    h2 lr = hi + lo * sl;
    p = __builtin_amdgcn_fdot2(lr, avh[k], p, false);
  }
  return p;
}
// accv += w * c (f16 source, f32 accum; fma_mix pattern)
__device__ __forceinline__ void acc_edge(float w, uint4 xu, float* accv){
  union { uint4 u; _Float16 e[8]; } ce; ce.u = xu;
  #pragma unroll
  for (int i = 0; i < 8; ++i) accv[i] += w * (float)ce.e[i];
}

// ---------------- W pack: B0h[256x256] = [Wl0; Wr0], B1h[256x128] = [Wl1; Wr1]
__global__ void convw_kernel(const float* __restrict__ Wl0, const float* __restrict__ Wr0,
                             const float* __restrict__ Wl1, const float* __restrict__ Wr1,
                             _Float16* __restrict__ B0h, _Float16* __restrict__ B1h){
  int t = blockIdx.x * blockDim.x + threadIdx.x;   // float4 units, 24576 total
  const float* s; _Float16* d; int off;
  if (t < 8192)      { s = Wl0; d = B0h;          off = t; }
  else if (t < 16384){ s = Wr0; d = B0h + 32768;  off = t - 8192; }
  else if (t < 20480){ s = Wl1; d = B1h;          off = t - 16384; }
  else               { s = Wr1; d = B1h + 16384;  off = t - 20480; }
  float4 f = ((const float4*)s)[off];
  h4 h = { (_Float16)f.x, (_Float16)f.y, (_Float16)f.z, (_Float16)f.w };
  *(h4*)(d + 4 * (size_t)off) = h;
}

// counting-sort scatter, LDS-aggregated. Emits perm AND iperm (inverse).
__global__ void scatter_kernel(const int* __restrict__ cnt, const int* __restrict__ hist,
                               int* __restrict__ cursor, int* __restrict__ perm,
                               int* __restrict__ iperm, int n){
  __shared__ int base[64];
  __shared__ int lh[64];
  __shared__ int lbase[64];
  __shared__ int ht[64];
  if (threadIdx.x < 64){
    lh[threadIdx.x] = 0;
    ht[threadIdx.x] = hist[threadIdx.x];
  }
  __syncthreads();
  if (threadIdx.x == 0){
    int acc = 0;
    for (int d = 63; d >= 0; --d){ base[d] = acc; acc += ht[d]; }  // descending deg
  }
  int i = blockIdx.x * blockDim.x + threadIdx.x;
  int d = 1, lr = 0;
  if (i < n){
    d = cnt[i]; d = (d < 1) ? 1 : (d > CAP ? CAP : d);
    lr = atomicAdd(&lh[d - 1], 1);
  }
  __syncthreads();
  if (threadIdx.x < 64 && lh[threadIdx.x] > 0)
    lbase[threadIdx.x] = atomicAdd(&cursor[threadIdx.x], lh[threadIdx.x]);
  __syncthreads();
  if (i < n){
    int pos = base[d - 1] + lbase[d - 1] + lr;
    perm[pos] = i;
    iperm[i] = pos;
  }
}

// ---------------- f16 MFMA GEMM body, tile 64 rows x 128 cols ----------------
// 4 waves: wave wx -> cols wx*32..+31 (4x2 MFMA tiles of 16x16x32_f16),
// BK=64, register-prefetch pipeline. LDS rows at exact 128 B with XOR swizzle
// (byte ^= (row&7)<<4): 24576 B total -> 6 blocks/CU. Epilogue restages f16 C
// tile in LDS. A read as f32 (layer 0, fused convert).
__device__ __forceinline__ void gemm_body(
    char* smem, const float* __restrict__ A32,
    const _Float16* __restrict__ Bw, _Float16* __restrict__ C, int n, int K,
    int bx, int by)
{
  char* Abase = smem;            // 64 rows x 128 B (swizzled)
  char* Bbase = smem + 8192;     // 128 rows x 128 B (swizzled)

  const int tid  = threadIdx.x;
  const int lane = tid & 63;
  const int wx   = tid >> 6;
  const int r0   = by * 64;
  const int cb   = bx * 128;
  const int m16  = lane & 15, quad = lane >> 4;

  f32x4 acc[4][2];
  #pragma unroll
  for (int i = 0; i < 4; ++i)
    #pragma unroll
    for (int j = 0; j < 2; ++j)
      acc[i][j] = (f32x4){0.f, 0.f, 0.f, 0.f};

  const int srow = tid >> 2;        // 0..63
  const int kq   = (tid & 3) << 4;  // 0,16,32,48 (elements)
  const int kb   = kq * 2;          // bytes within row
  const int swz  = (srow & 7) << 4; // write-side row swizzle

  uint4 ra[2], rb[2][2];
  const uint4 z = {0u, 0u, 0u, 0u};

  if (r0 + srow < n){
    const float* p = A32 + (size_t)(r0 + srow) * K + kq;
    ra[0] = pack8(*(const float4*)(p),     *(const float4*)(p + 4));
    ra[1] = pack8(*(const float4*)(p + 8), *(const float4*)(p + 12));
  } else { ra[0] = z; ra[1] = z; }
  #pragma unroll
  for (int v = 0; v < 2; ++v){
    const _Float16* p = Bw + (size_t)(cb + v * 64 + srow) * K + kq;
    rb[v][0] = *(const uint4*)(p);
    rb[v][1] = *(const uint4*)(p + 8);
  }

  const int nt = K >> 6;
  for (int t = 0; t < nt; ++t){
    *(uint4*)(Abase + srow * 128 + (kb ^ swz))        = ra[0];
    *(uint4*)(Abase + srow * 128 + ((kb + 16) ^ swz)) = ra[1];
    #pragma unroll
    for (int v = 0; v < 2; ++v){
      *(uint4*)(Bbase + (v * 64 + srow) * 128 + (kb ^ swz))        = rb[v][0];
      *(uint4*)(Bbase + (v * 64 + srow) * 128 + ((kb + 16) ^ swz)) = rb[v][1];
    }
    __syncthreads();
    if (t + 1 < nt){
      int kt = (t + 1) << 6;
      if (r0 + srow < n){
        const float* p = A32 + (size_t)(r0 + srow) * K + kt + kq;
        ra[0] = pack8(*(const float4*)(p),     *(const float4*)(p + 4));
        ra[1] = pack8(*(const float4*)(p + 8), *(const float4*)(p + 12));
      }
      #pragma unroll
      for (int v = 0; v < 2; ++v){
        const _Float16* p = Bw + (size_t)(cb + v * 64 + srow) * K + kt + kq;
        rb[v][0] = *(const uint4*)(p);
        rb[v][1] = *(const uint4*)(p + 8);
      }
    }
    const int swr = (m16 & 7) << 4;   // read-side row swizzle
    #pragma unroll
    for (int ks = 0; ks < 2; ++ks){
      const int k0 = ks * 32 + quad * 8;
      const int cbyte = (k0 * 2) ^ swr;
      h8 a[4], b[2];
      #pragma unroll
      for (int i = 0; i < 4; ++i)
        a[i] = *(const h8*)(Abase + (i * 16 + m16) * 128 + cbyte);
      #pragma unroll
      for (int j = 0; j < 2; ++j)
        b[j] = *(const h8*)(Bbase + (wx * 32 + j * 16 + m16) * 128 + cbyte);
      #pragma unroll
      for (int i = 0; i < 4; ++i)
        #pragma unroll
        for (int j = 0; j < 2; ++j)
          acc[i][j] = __builtin_amdgcn_mfma_f32_16x16x32_f16(a[i], b[j], acc[i][j], 0, 0, 0);
    }
    __syncthreads();
  }

  _Float16* Csm = (_Float16*)smem;
  #pragma unroll
  for (int i = 0; i < 4; ++i)
    #pragma unroll
    for (int r = 0; r < 4; ++r){
      int lrow = i * 16 + quad * 4 + r;
      _Float16* cp = Csm + lrow * 136 + wx * 32 + m16;
      #pragma unroll
      for (int j = 0; j < 2; ++j)
        cp[j * 16] = (_Float16)acc[i][j][r];
    }
  __syncthreads();
  #pragma unroll
  for (int v = 0; v < 4; ++v){
    int idx = v * 256 + tid;            // 1024 chunks of 8 f16
    int row = idx >> 4, cx = (idx & 15) * 8;
    if (r0 + row < n)
      *(uint4*)(C + (size_t)(r0 + row) * 256 + cb + cx)
        = *(const uint4*)(Csm + row * 136 + cx);
  }
}

// ---------------- fused: layer-0 GEMM  ∥  edge binning (pass 1) --------------
// pass1 bins edges by coarse bucket dst>>8 (196 buckets of 256 nodes): per
// block LDS-histogram its 2048 edges, ONE global cursor atomic per
// (block,bucket), then write packed (loc<<24|src) runs. Coalesced writes, no
// per-edge global atomics. pass1 blocks dispatched first, gemm fills behind.
__global__ __launch_bounds__(256) void gemm_pass1(
    const float* __restrict__ A32, const _Float16* __restrict__ Bw,
    _Float16* __restrict__ C, int n,
    const int* __restrict__ ei, int* __restrict__ bins, int* __restrict__ bcursor,
    int e_orig, int etot, int NP)
{
  __shared__ __align__(16) char smem[24576];
  const int lin = blockIdx.x;
  if (lin >= NP){
    int gi = lin - NP;                       // same dispatch order as grid (2, nby)
    gemm_body(smem, A32, Bw, C, n, 256, gi & 1, gi >> 1);
  } else {
    int* lcnt  = (int*)smem;                 // 196
    int* gbase = lcnt + 256;                 // 196
    const int tid = threadIdx.x;
    if (tid < 196) lcnt[tid] = 0;
    __syncthreads();
    const int base = lin * 2048 + tid;
    int pk[8], bk[8], lp[8];
    #pragma unroll
    for (int k = 0; k < 8; ++k){
      int i = base + k * 256;
      bk[k] = -1;
      if (i < etot){
        int src, dst;
        if (i < e_orig){ src = ei[i]; dst = ei[e_orig + i]; }
        else { src = i - e_orig; dst = src; }           // self loops
        bk[k] = dst >> 8;
        pk[k] = ((dst & 255) << 24) | src;              // src < 2^24
      }
    }
    #pragma unroll
    for (int k = 0; k < 8; ++k)
      if (bk[k] >= 0) lp[k] = atomicAdd(&lcnt[bk[k]], 1);
    __syncthreads();
    if (tid < 196 && lcnt[tid] > 0)
      gbase[tid] = atomicAdd(&bcursor[tid], lcnt[tid]);
    __syncthreads();
    #pragma unroll
    for (int k = 0; k < 8; ++k)
      if (bk[k] >= 0){
        int p = gbase[bk[k]] + lp[k];
        if (p < BCAP) bins[(size_t)bk[k] * BCAP + p] = pk[k];
      }
  }
}

// ---------------- pass 2: per-bucket adjacency materialization ---------------
__global__ __launch_bounds__(256) void pass2_kernel(
    const int* __restrict__ bins, const int* __restrict__ bcursor,
    int* __restrict__ cnt, int* __restrict__ col2, int* __restrict__ hist, int n)
{
  __shared__ int stage[256 * CAP];   // 64 KB
  __shared__ int lcnt2[256];
  __shared__ int lh[64];
  const int b = blockIdx.x, tid = threadIdx.x;
  lcnt2[tid] = 0;
  if (tid < 64) lh[tid] = 0;
  __syncthreads();
  int ecnt = bcursor[b]; if (ecnt > BCAP) ecnt = BCAP;
  for (int i = tid; i < ecnt; i += 256){
    int v = bins[(size_t)b * BCAP + i];
    int src = v & 0xFFFFFF;
    int loc = ((unsigned)v) >> 24;
    int pos = atomicAdd(&lcnt2[loc], 1);
    if (pos < CAP) stage[loc * CAP + pos] = src;
  }
  __syncthreads();
  int node = b * 256 + tid;
  if (node < n){
    int d = lcnt2[tid];
    cnt[node] = d;
    int dc = d < 1 ? 1 : (d > CAP ? CAP : d);
    atomicAdd(&lh[dc - 1], 1);
  }
  __syncthreads();
  const uint4* sg = (const uint4*)stage;
  uint4* c4 = (uint4*)col2;
  for (int k2 = tid; k2 < 4096; k2 += 256){       // 4096 uint4 = 64 KB
    int nd = b * 256 + (k2 >> 4);
    if (nd < n) c4[(size_t)nd * 16 + (k2 & 15)] = sg[k2];
  }
  if (tid < 64 && lh[tid] > 0) atomicAdd(&hist[tid], lh[tid]);
}

// ---------------- fused: layer-0 aggregation + layer-1 GEMM ------------------
// Block owns 64 perm-consecutive slots. Phase A: aggregate them (4 rounds of
// 16 nodes, 16-lane groups, diet pipeline) writing h into a swizzled LDS tile
// (no H16 global round-trip). Phase B: XLR1[slots] = H x [Wl1;Wr1]^T straight
// from LDS (A-read is free), written in SLOT order -> agg_down gathers via
// iperm. Tile 64x256, 4 waves x 64 cols, K=128 in 2 BK=64 steps with register
// prefetch of step-1 B. LDS 53.8 KB -> 3 blocks/CU.
__global__ __launch_bounds__(256) void agg_gemm1(
    const _Float16* __restrict__ XLR, const int* __restrict__ col2,
    const int* __restrict__ cnt, const int* __restrict__ perm,
    const float* __restrict__ att, const float* __restrict__ bias,
    const _Float16* __restrict__ B1h, _Float16* __restrict__ XLR1, int n)
{
  __shared__ __align__(16) char smem[53760];
  char* Hs = smem;                                  // 64 rows x 256 B, swizzled
  char* Bs = smem + 16384;                          // 256 rows x 128 B, swizzled
  int (*idxs)[72] = (int(*)[72])(smem + 49152);     // 16 x 72

  const int tid  = threadIdx.x;
  const int lane = tid & 63;
  const int g = lane >> 4, ll = lane & 15, gbase = g << 4;
  const int nlq = ((tid >> 6) << 2) + g;            // 0..15
  const int slot0 = blockIdx.x * 64;
  const int c0 = 8 * ll;

  // ---- Phase A: aggregate 64 slots in 4 rounds of 16 ----
  for (int rnd = 0; rnd < 4; ++rnd){
    const int lrow = rnd * 16 + nlq;
    const int slot = slot0 + lrow;
    const bool valid = slot < n;
    const int node = valid ? perm[slot] : 0;
    int deg = 0;
    if (valid){ deg = cnt[node]; if (deg > CAP) deg = CAP; }

    h2 xrh[4], avh[4];
    {
      union { uint4 u; h2 v[4]; } xc;
      xc.u = (uint4){0u,0u,0u,0u};
      if (valid) xc.u = *(const uint4*)(XLR + (size_t)node * 256 + 128 + c0);
      #pragma unroll
      for (int k = 0; k < 4; ++k) xrh[k] = xc.v[k];
      #pragma unroll
      for (int k = 0; k < 4; ++k)
        avh[k] = (h2){ (_Float16)att[c0 + 2*k], (_Float16)att[c0 + 2*k + 1] };
    }
    {
      int sq[4];
      #pragma unroll
      for (int q = 0; q < 4; ++q)
        sq[q] = (valid && ll + 16*q < deg) ? col2[(size_t)node * CAP + ll + 16*q] : 0;
      int s0 = __shfl(sq[0], gbase);
      #pragma unroll
      for (int q = 0; q < 4; ++q)
        idxs[nlq][ll + 16*q] = (ll + 16*q < deg) ? sq[q] : s0;
      if (ll < 8) idxs[nlq][64 + ll] = s0;
    }
    const int* idxp = idxs[nlq];

    float l = 0.f, accv[8];
    #pragma unroll
    for (int i = 0; i < 8; ++i) accv[i] = 0.f;

    uint4 x0, x1, x2, x3, x4, x5, x6, x7;
    {
      int e0 = idxp[0], e1 = idxp[1], e2 = idxp[2], e3 = idxp[3];
      int e4 = idxp[4], e5 = idxp[5], e6 = idxp[6], e7 = idxp[7];
      x0 = *(const uint4*)(XLR + (size_t)e0 * 256 + c0);
      x1 = *(const uint4*)(XLR + (size_t)e1 * 256 + c0);
      x2 = *(const uint4*)(XLR + (size_t)e2 * 256 + c0);
      x3 = *(const uint4*)(XLR + (size_t)e3 * 256 + c0);
      x4 = *(const uint4*)(XLR + (size_t)e4 * 256 + c0);
      x5 = *(const uint4*)(XLR + (size_t)e5 * 256 + c0);
      x6 = *(const uint4*)(XLR + (size_t)e6 * 256 + c0);
      x7 = *(const uint4*)(XLR + (size_t)e7 * 256 + c0);
    }

    int j = 0;
    for (; j + 4 <= deg; j += 4){
      uint4 y0 = x0, y1 = x1, y2 = x2, y3 = x3;
      x0 = x4; x1 = x5; x2 = x6; x3 = x7;
      int e8  = idxp[j + 8],  e9  = idxp[j + 9];
      int e10 = idxp[j + 10], e11 = idxp[j + 11];
      x4 = *(const uint4*)(XLR + (size_t)e8  * 256 + c0);
      x5 = *(const uint4*)(XLR + (size_t)e9  * 256 + c0);
      x6 = *(const uint4*)(XLR + (size_t)e10 * 256 + c0);
      x7 = *(const uint4*)(XLR + (size_t)e11 * 256 + c0);
      float p0 = edge_logit(y0, xrh, avh);
      float p1 = edge_logit(y1, xrh, avh);
      float p2 = edge_logit(y2, xrh, avh);
      float p3 = edge_logit(y3, xrh, avh);
      p0 += __shfl_xor(p0, 1);  p1 += __shfl_xor(p1, 1);
      p2 += __shfl_xor(p2, 1);  p3 += __shfl_xor(p3, 1);
      p0 += __shfl_xor(p0, 2);  p1 += __shfl_xor(p1, 2);
      p2 += __shfl_xor(p2, 2);  p3 += __shfl_xor(p3, 2);
      float w0 = __expf(p0), w1 = __expf(p1), w2 = __expf(p2), w3 = __expf(p3);
      l += (w0 + w1) + (w2 + w3);
      acc_edge(w0, y0, accv); acc_edge(w1, y1, accv);
      acc_edge(w2, y2, accv); acc_edge(w3, y3, accv);
    }
    #pragma unroll
    for (int r = 0; r < 3; ++r){
      if (j + r < deg){
        uint4 xe = (r == 0) ? x0 : ((r == 1) ? x1 : x2);
        float p = edge_logit(xe, xrh, avh);
        p += __shfl_xor(p, 1);
        p += __shfl_xor(p, 2);
        float w = __expf(p);
        l += w;
        acc_edge(w, xe, accv);
      }
    }
    if (valid){
      float inv = (deg > 0) ? 1.f / l : 0.f;
      union { h8 h; uint4 u; } o;
      #pragma unroll
      for (int i = 0; i < 8; ++i)
        o.h[i] = (_Float16)(accv[i] * inv + bias[c0 + i]);
      *(uint4*)(Hs + lrow * 256 + ((c0 * 2) ^ ((lrow & 7) << 4))) = o.u;
    }
  }
  __syncthreads();

  // ---- Phase B: XLR1[slot0..+64) = H(64x128) x B1h(256x128)^T ----
  const int wx = tid >> 6;
  const int m16 = lane & 15, quad = lane >> 4;
  const int swr = (m16 & 7) << 4;
  f32x4 acc[4][4];
  #pragma unroll
  for (int i = 0; i < 4; ++i)
    #pragma unroll
    for (int j = 0; j < 4; ++j)
      acc[i][j] = (f32x4){0.f, 0.f, 0.f, 0.f};

  uint4 rbf[8];
  {
    const _Float16* p = B1h + (size_t)tid * 128;      // row tid, step0 (k 0..63)
    #pragma unroll
    for (int k = 0; k < 8; ++k) rbf[k] = *(const uint4*)(p + k * 8);
  }
  #pragma unroll
  for (int k = 0; k < 8; ++k)
    *(uint4*)(Bs + tid * 128 + ((k * 16) ^ ((tid & 7) << 4))) = rbf[k];
  __syncthreads();
  {
    const _Float16* p = B1h + (size_t)tid * 128 + 64;  // step1 prefetch
    #pragma unroll
    for (int k = 0; k < 8; ++k) rbf[k] = *(const uint4*)(p + k * 8);
  }
  #pragma unroll
  for (int ks = 0; ks < 2; ++ks){
    const int kw = ks * 32 + quad * 8;
    h8 a[4], b[4];
    #pragma unroll
    for (int i = 0; i < 4; ++i)
      a[i] = *(const h8*)(Hs + (i * 16 + m16) * 256 + ((kw * 2) ^ swr));
    #pragma unroll
    for (int j = 0; j < 4; ++j)
      b[j] = *(const h8*)(Bs + (wx * 64 + j * 16 + m16) * 128 + ((kw * 2) ^ swr));
    #pragma unroll
    for (int i = 0; i < 4; ++i)
      #pragma unroll
      for (int j = 0; j < 4; ++j)
        acc[i][j] = __builtin_amdgcn_mfma_f32_16x16x32_f16(a[i], b[j], acc[i][j], 0, 0, 0);
  }
  __syncthreads();
  #pragma unroll
  for (int k = 0; k < 8; ++k)
    *(uint4*)(Bs + tid * 128 + ((k * 16) ^ ((tid & 7) << 4))) = rbf[k];
  __syncthreads();
  #pragma unroll
  for (int ks = 0; ks < 2; ++ks){
    const int kw = ks * 32 + quad * 8;
    h8 a[4], b[4];
    #pragma unroll
    for (int i = 0; i < 4; ++i)
      a[i] = *(const h8*)(Hs + (i * 16 + m16) * 256 + (((64 + kw) * 2) ^ swr));
    #pragma unroll
    for (int j = 0; j < 4; ++j)
      b[j] = *(const h8*)(Bs + (wx * 64 + j * 16 + m16) * 128 + ((kw * 2) ^ swr));
    #pragma unroll
    for (int i = 0; i < 4; ++i)
      #pragma unroll
      for (int j = 0; j < 4; ++j)
        acc[i][j] = __builtin_amdgcn_mfma_f32_16x16x32_f16(a[i], b[j], acc[i][j], 0, 0, 0);
  }
  __syncthreads();   // Hs/Bs dead -> reuse as Csm

  _Float16* Csm = (_Float16*)smem;   // [64][264]
  #pragma unroll
  for (int i = 0; i < 4; ++i)
    #pragma unroll
    for (int r = 0; r < 4; ++r){
      int lrow = i * 16 + quad * 4 + r;
      _Float16* cp = Csm + lrow * 264 + wx * 64 + m16;
      #pragma unroll
      for (int j = 0; j < 4; ++j)
        cp[j * 16] = (_Float16)acc[i][j][r];
    }
  __syncthreads();
  #pragma unroll
  for (int v = 0; v < 8; ++v){
    int idx = v * 256 + tid;            // 2048 chunks of 8 f16
    int row = idx >> 5, cx = (idx & 31) * 8;
    if (slot0 + row < n)
      *(uint4*)(XLR1 + (size_t)(slot0 + row) * 256 + cx)
        = *(const uint4*)(Csm + row * 264 + cx);
  }
}

// ---------------- layer-1 aggregation fused with down_proj -------------------
// XLR1 is SLOT-ordered: gathers translate src via iperm; xr read at slot row.
__global__ __launch_bounds__(256) void agg_down(
    const _Float16* __restrict__ XLR1, const int* __restrict__ col2,
    const int* __restrict__ cnt, const int* __restrict__ perm,
    const int* __restrict__ iperm,
    const float* __restrict__ att,
    const float* __restrict__ bias, const float* __restrict__ dW,
    const float* __restrict__ db, float* __restrict__ out, int n)
{
  __shared__ float dwb[32][129];
  __shared__ float hsm[16][128];
  __shared__ int idxs[16][72];
  for (int i = threadIdx.x; i < 32 * 128; i += 256)
    dwb[i >> 7][i & 127] = dW[i];

  const int lane  = threadIdx.x & 63;
  const int g     = lane >> 4;
  const int ll    = lane & 15;
  const int gbase = g << 4;
  const int nl    = ((threadIdx.x >> 6) << 2) + g;   // 0..15
  const int slot  = blockIdx.x * 16 + nl;
  const bool valid = slot < n;
  const int node = valid ? perm[slot] : 0;
  int deg = 0;
  if (valid){ deg = cnt[node]; if (deg > CAP) deg = CAP; }
  const int c0 = 8 * ll;

  h2 xrh[4], avh[4];
  {
    union { uint4 u; h2 v[4]; } xc;
    xc.u = (uint4){0u,0u,0u,0u};
    if (valid) xc.u = *(const uint4*)(XLR1 + (size_t)slot * 256 + 128 + c0);
    #pragma unroll
    for (int k = 0; k < 4; ++k) xrh[k] = xc.v[k];
    #pragma unroll
    for (int k = 0; k < 4; ++k)
      avh[k] = (h2){ (_Float16)att[c0 + 2*k], (_Float16)att[c0 + 2*k + 1] };
  }

  {
    int sq[4];
    #pragma unroll
    for (int q = 0; q < 4; ++q)
      sq[q] = (valid && ll + 16*q < deg)
                ? iperm[col2[(size_t)node * CAP + ll + 16*q]] : 0;
    int s0 = __shfl(sq[0], gbase);
    #pragma unroll
    for (int q = 0; q < 4; ++q)
      idxs[nl][ll + 16*q] = (ll + 16*q < deg) ? sq[q] : s0;
    if (ll < 8) idxs[nl][64 + ll] = s0;
  }
  const int* idxp = idxs[nl];

  float l = 0.f, accv[8];
  #pragma unroll
  for (int i = 0; i < 8; ++i) accv[i] = 0.f;

  uint4 x0, x1, x2, x3, x4, x5, x6, x7;
  {
    int e0 = idxp[0], e1 = idxp[1], e2 = idxp[2], e3 = idxp[3];
    int e4 = idxp[4], e5 = idxp[5], e6 = idxp[6], e7 = idxp[7];
    x0 = *(const uint4*)(XLR1 + (size_t)e0 * 256 + c0);
    x1 = *(const uint4*)(XLR1 + (size_t)e1 * 256 + c0);
    x2 = *(const uint4*)(XLR1 + (size_t)e2 * 256 + c0);
    x3 = *(const uint4*)(XLR1 + (size_t)e3 * 256 + c0);
    x4 = *(const uint4*)(XLR1 + (size_t)e4 * 256 + c0);
    x5 = *(const uint4*)(XLR1 + (size_t)e5 * 256 + c0);
    x6 = *(const uint4*)(XLR1 + (size_t)e6 * 256 + c0);
    x7 = *(const uint4*)(XLR1 + (size_t)e7 * 256 + c0);
  }

  int j = 0;
  for (; j + 4 <= deg; j += 4){
    uint4 y0 = x0, y1 = x1, y2 = x2, y3 = x3;
    x0 = x4; x1 = x5; x2 = x6; x3 = x7;
    int e8  = idxp[j + 8],  e9  = idxp[j + 9];
    int e10 = idxp[j + 10], e11 = idxp[j + 11];
    x4 = *(const uint4*)(XLR1 + (size_t)e8  * 256 + c0);
    x5 = *(const uint4*)(XLR1 + (size_t)e9  * 256 + c0);
    x6 = *(const uint4*)(XLR1 + (size_t)e10 * 256 + c0);
    x7 = *(const uint4*)(XLR1 + (size_t)e11 * 256 + c0);
    float p0 = edge_logit(y0, xrh, avh);
    float p1 = edge_logit(y1, xrh, avh);
    float p2 = edge_logit(y2, xrh, avh);
    float p3 = edge_logit(y3, xrh, avh);
    p0 += __shfl_xor(p0, 1);  p1 += __shfl_xor(p1, 1);
    p2 += __shfl_xor(p2, 1);  p3 += __shfl_xor(p3, 1);
    p0 += __shfl_xor(p0, 2);  p1 += __shfl_xor(p1, 2);
    p2 += __shfl_xor(p2, 2);  p3 += __shfl_xor(p3, 2);
    float w0 = __expf(p0), w1 = __expf(p1), w2 = __expf(p2), w3 = __expf(p3);
    l += (w0 + w1) + (w2 + w3);
    acc_edge(w0, y0, accv); acc_edge(w1, y1, accv);
    acc_edge(w2, y2, accv); acc_edge(w3, y3, accv);
  }
  #pragma unroll
  for (int r = 0; r < 3; ++r){
    if (j + r < deg){
      uint4 xe = (r == 0) ? x0 : ((r == 1) ? x1 : x2);
      float p = edge_logit(xe, xrh, avh);
      p += __shfl_xor(p, 1);
      p += __shfl_xor(p, 2);
      float w = __expf(p);
      l += w;
      acc_edge(w, xe, accv);
    }
  }
  {
    float inv = (deg > 0) ? 1.f / l : 0.f;
    #pragma unroll
    for (int i = 0; i < 8; ++i)
      hsm[nl][c0 + i] = accv[i] * inv + bias[c0 + i];
  }
  __syncthreads();

  // ---- down phase: 512 outputs over 256 threads (2 each) ----
  const int o = threadIdx.x & 31;
  #pragma unroll
  for (int h2i = 0; h2i < 2; ++h2i){
    int nl2 = (threadIdx.x >> 5) + h2i * 8;
    int slot2 = blockIdx.x * 16 + nl2;
    float sum = 0.f;
    #pragma unroll 8
    for (int k = 0; k < 128; ++k)
      sum += hsm[nl2][k] * dwb[o][k];
    if (slot2 < n)
      out[(size_t)perm[slot2] * 32 + o] = sum + db[o];
  }
}

extern "C" void kernel_launch(void* const* d_in, const int* in_sizes, int n_in,
                              void* d_out, int out_size, void* d_ws, size_t ws_size,
                              hipStream_t stream) {
  const float* x     = (const float*)d_in[0];
  const int*   ei    = (const int*)  d_in[1];
  const float* Wl0   = (const float*)d_in[2];
  const float* Wr0   = (const float*)d_in[3];
  const float* att0  = (const float*)d_in[4];
  const float* b0    = (const float*)d_in[5];
  const float* Wl1   = (const float*)d_in[6];
  const float* Wr1   = (const float*)d_in[7];
  const float* att1  = (const float*)d_in[8];
  const float* b1    = (const float*)d_in[9];
  const float* dW    = (const float*)d_in[10];
  const float* db    = (const float*)d_in[11];
  float* out = (float*)d_out;

  const int n    = in_sizes[0] / 256;      // 50000
  const int e    = in_sizes[1] / 2;        // 800000
  const int etot = e + n;

  // workspace layout
  _Float16* XLR16 = (_Float16*)d_ws;                    // n*256 f16 (layer-0, node order)
  _Float16* XLR1  = XLR16 + (size_t)n * 256;            // n*256 f16 (layer-1, slot order)
  int* col2 = (int*)(XLR1 + (size_t)n * 256);           // n*CAP
  int* cnt  = col2 + (size_t)n * CAP;                   // n
  int* hist    = cnt + n;                               // 64
  int* cursor  = hist + 64;                             // 64
  int* bcursor = cursor + 64;                           // 256 (196 used)
  int* perm    = bcursor + 256;                         // n
  int* iperm   = perm + n;                              // n
  _Float16* B0h = (_Float16*)(iperm + ((n + 3) & ~3));  // 256*256 f16
  _Float16* B1h = B0h + 65536;                          // 256*128 f16
  int* bins = (int*)XLR1;   // 196*BCAP ints = 4.8 MB, aliases XLR1 (dead till agg_gemm1)

  // zero cnt + hist + cursor + bcursor in one shot (contiguous)
  (void)hipMemsetAsync(cnt, 0, ((size_t)n + 384) * sizeof(int), stream);
  convw_kernel<<<96, 256, 0, stream>>>(Wl0, Wr0, Wl1, Wr1, B0h, B1h);

  // fused: pass1 binning (NP blocks, dispatched first) ∥ layer-0 GEMM (NG)
  const int NP = (etot + 2047) / 2048;          // 416
  const int NG = 2 * ((n + 63) / 64);           // 1564
  gemm_pass1<<<NP + NG, 256, 0, stream>>>(x, B0h, XLR16, n, ei, bins, bcursor,
                                          e, etot, NP);

  const int NB2 = (n + 255) / 256;              // 196
  pass2_kernel<<<NB2, 256, 0, stream>>>(bins, bcursor, cnt, col2, hist, n);
  scatter_kernel<<<(n + 255) / 256, 256, 0, stream>>>(cnt, hist, cursor, perm, iperm, n);

  // fused: layer-0 aggregation + layer-1 GEMM (H never leaves LDS)
  agg_gemm1<<<(n + 63) / 64, 256, 0, stream>>>(XLR16, col2, cnt, perm, att0, b0,
                                               B1h, XLR1, n);
  // layer-1 agg + down proj fused (slot-ordered gathers via iperm)
  agg_down<<<(n + 15) / 16, 256, 0, stream>>>(XLR1, col2, cnt, perm, iperm,
                                              att1, b1, dW, db, out, n);
}

// Round 11
// 288.491 us; speedup vs baseline: 1.0449x; 1.0449x over previous
//
#include <hip/hip_runtime.h>

#define CAP 64
#define BCAP 6144   // per-bucket edge capacity (mean 4352 + 27 sigma)

typedef _Float16 h8 __attribute__((ext_vector_type(8)));
typedef _Float16 h4 __attribute__((ext_vector_type(4)));
typedef _Float16 h2 __attribute__((ext_vector_type(2)));
typedef float f32x4 __attribute__((ext_vector_type(4)));

__device__ __forceinline__ uint4 pack8(float4 a, float4 b){
  union { h8 h; uint4 u; } cv;
  cv.h = (h8){ (_Float16)a.x, (_Float16)a.y, (_Float16)a.z, (_Float16)a.w,
               (_Float16)b.x, (_Float16)b.y, (_Float16)b.z, (_Float16)b.w };
  return cv.u;
}

// packed-f16 logit partial: sum_k dot2(lrelu(c2k + xr2k), att2k), f32 accum
__device__ __forceinline__ float edge_logit(uint4 xu, const h2* xrh, const h2* avh){
  union { uint4 u; h2 v[4]; } cu; cu.u = xu;
  const h2 z2 = { (_Float16)0.f, (_Float16)0.f };
  const h2 sl = { (_Float16)0.2f, (_Float16)0.2f };
  float p = 0.f;
  #pragma unroll
  for (int k = 0; k < 4; ++k){
    h2 t  = cu.v[k] + xrh[k];
    h2 hi = __builtin_elementwise_max(t, z2);
    h2 lo = __builtin_elementwise_min(t, z2);
    h2 lr = hi + lo * sl;
    p = __builtin_amdgcn_fdot2(lr, avh[k], p, false);
  }
  return p;
}
// accv += w * c (f16 source, f32 accum; fma_mix pattern)
__device__ __forceinline__ void acc_edge(float w, uint4 xu, float* accv){
  union { uint4 u; _Float16 e[8]; } ce; ce.u = xu;
  #pragma unroll
  for (int i = 0; i < 8; ++i) accv[i] += w * (float)ce.e[i];
}

// ---------------- W pack: B0h[256x256] = [Wl0; Wr0], B1h[256x128] = [Wl1; Wr1]
__global__ void convw_kernel(const float* __restrict__ Wl0, const float* __restrict__ Wr0,
                             const float* __restrict__ Wl1, const float* __restrict__ Wr1,
                             _Float16* __restrict__ B0h, _Float16* __restrict__ B1h){
  int t = blockIdx.x * blockDim.x + threadIdx.x;   // float4 units, 24576 total
  const float* s; _Float16* d; int off;
  if (t < 8192)      { s = Wl0; d = B0h;          off = t; }
  else if (t < 16384){ s = Wr0; d = B0h + 32768;  off = t - 8192; }
  else if (t < 20480){ s = Wl1; d = B1h;          off = t - 16384; }
  else               { s = Wr1; d = B1h + 16384;  off = t - 20480; }
  float4 f = ((const float4*)s)[off];
  h4 h = { (_Float16)f.x, (_Float16)f.y, (_Float16)f.z, (_Float16)f.w };
  *(h4*)(d + 4 * (size_t)off) = h;
}

// counting-sort scatter, LDS-aggregated: local rank via LDS atomics, one
// global cursor atomic per (block, bucket). Within-bucket order arbitrary.
__global__ void scatter_kernel(const int* __restrict__ cnt, const int* __restrict__ hist,
                               int* __restrict__ cursor, int* __restrict__ perm, int n){
  __shared__ int base[64];
  __shared__ int lh[64];
  __shared__ int lbase[64];
  __shared__ int ht[64];
  if (threadIdx.x < 64){
    lh[threadIdx.x] = 0;
    ht[threadIdx.x] = hist[threadIdx.x];
  }
  __syncthreads();
  if (threadIdx.x == 0){
    int acc = 0;
    for (int d = 63; d >= 0; --d){ base[d] = acc; acc += ht[d]; }  // descending deg
  }
  int i = blockIdx.x * blockDim.x + threadIdx.x;
  int d = 1, lr = 0;
  if (i < n){
    d = cnt[i]; d = (d < 1) ? 1 : (d > CAP ? CAP : d);
    lr = atomicAdd(&lh[d - 1], 1);
  }
  __syncthreads();
  if (threadIdx.x < 64 && lh[threadIdx.x] > 0)
    lbase[threadIdx.x] = atomicAdd(&cursor[threadIdx.x], lh[threadIdx.x]);
  __syncthreads();
  if (i < n)
    perm[base[d - 1] + lbase[d - 1] + lr] = i;
}

// ---------------- f16 MFMA GEMM body, tile 64 rows x 128 cols ----------------
// 4 waves: wave wx -> cols wx*32..+31 (4x2 MFMA tiles of 16x16x32_f16),
// BK=64, register-prefetch pipeline. LDS rows at exact 128 B with XOR swizzle
// (byte ^= (row&7)<<4): 24576 B total -> 6 blocks/CU. Epilogue restages f16 C
// tile in LDS. A read as f32 (layer 0, fused convert) or f16 (layer 1).
__device__ __forceinline__ void gemm_body(
    char* smem, const float* __restrict__ A32, const _Float16* __restrict__ A16,
    const _Float16* __restrict__ Bw, _Float16* __restrict__ C, int n, int K,
    int bx, int by)
{
  char* Abase = smem;            // 64 rows x 128 B (swizzled)
  char* Bbase = smem + 8192;     // 128 rows x 128 B (swizzled)

  const int tid  = threadIdx.x;
  const int lane = tid & 63;
  const int wx   = tid >> 6;
  const int r0   = by * 64;
  const int cb   = bx * 128;
  const int m16  = lane & 15, quad = lane >> 4;

  f32x4 acc[4][2];
  #pragma unroll
  for (int i = 0; i < 4; ++i)
    #pragma unroll
    for (int j = 0; j < 2; ++j)
      acc[i][j] = (f32x4){0.f, 0.f, 0.f, 0.f};

  const int srow = tid >> 2;        // 0..63
  const int kq   = (tid & 3) << 4;  // 0,16,32,48 (elements)
  const int kb   = kq * 2;          // bytes within row
  const int swz  = (srow & 7) << 4; // write-side row swizzle

  uint4 ra[2], rb[2][2];
  const uint4 z = {0u, 0u, 0u, 0u};

  if (r0 + srow < n){
    if (A32){
      const float* p = A32 + (size_t)(r0 + srow) * K + kq;
      ra[0] = pack8(*(const float4*)(p),     *(const float4*)(p + 4));
      ra[1] = pack8(*(const float4*)(p + 8), *(const float4*)(p + 12));
    } else {
      const _Float16* p = A16 + (size_t)(r0 + srow) * K + kq;
      ra[0] = *(const uint4*)(p);
      ra[1] = *(const uint4*)(p + 8);
    }
  } else { ra[0] = z; ra[1] = z; }
  #pragma unroll
  for (int v = 0; v < 2; ++v){
    const _Float16* p = Bw + (size_t)(cb + v * 64 + srow) * K + kq;
    rb[v][0] = *(const uint4*)(p);
    rb[v][1] = *(const uint4*)(p + 8);
  }

  const int nt = K >> 6;
  for (int t = 0; t < nt; ++t){
    *(uint4*)(Abase + srow * 128 + (kb ^ swz))        = ra[0];
    *(uint4*)(Abase + srow * 128 + ((kb + 16) ^ swz)) = ra[1];
    #pragma unroll
    for (int v = 0; v < 2; ++v){
      *(uint4*)(Bbase + (v * 64 + srow) * 128 + (kb ^ swz))        = rb[v][0];
      *(uint4*)(Bbase + (v * 64 + srow) * 128 + ((kb + 16) ^ swz)) = rb[v][1];
    }
    __syncthreads();
    if (t + 1 < nt){
      int kt = (t + 1) << 6;
      if (r0 + srow < n){
        if (A32){
          const float* p = A32 + (size_t)(r0 + srow) * K + kt + kq;
          ra[0] = pack8(*(const float4*)(p),     *(const float4*)(p + 4));
          ra[1] = pack8(*(const float4*)(p + 8), *(const float4*)(p + 12));
        } else {
          const _Float16* p = A16 + (size_t)(r0 + srow) * K + kt + kq;
          ra[0] = *(const uint4*)(p);
          ra[1] = *(const uint4*)(p + 8);
        }
      }
      #pragma unroll
      for (int v = 0; v < 2; ++v){
        const _Float16* p = Bw + (size_t)(cb + v * 64 + srow) * K + kt + kq;
        rb[v][0] = *(const uint4*)(p);
        rb[v][1] = *(const uint4*)(p + 8);
      }
    }
    const int swr = (m16 & 7) << 4;   // read-side row swizzle
    #pragma unroll
    for (int ks = 0; ks < 2; ++ks){
      const int k0 = ks * 32 + quad * 8;
      const int cbyte = (k0 * 2) ^ swr;
      h8 a[4], b[2];
      #pragma unroll
      for (int i = 0; i < 4; ++i)
        a[i] = *(const h8*)(Abase + (i * 16 + m16) * 128 + cbyte);
      #pragma unroll
      for (int j = 0; j < 2; ++j)
        b[j] = *(const h8*)(Bbase + (wx * 32 + j * 16 + m16) * 128 + cbyte);
      #pragma unroll
      for (int i = 0; i < 4; ++i)
        #pragma unroll
        for (int j = 0; j < 2; ++j)
          acc[i][j] = __builtin_amdgcn_mfma_f32_16x16x32_f16(a[i], b[j], acc[i][j], 0, 0, 0);
    }
    __syncthreads();
  }

  _Float16* Csm = (_Float16*)smem;
  #pragma unroll
  for (int i = 0; i < 4; ++i)
    #pragma unroll
    for (int r = 0; r < 4; ++r){
      int lrow = i * 16 + quad * 4 + r;
      _Float16* cp = Csm + lrow * 136 + wx * 32 + m16;
      #pragma unroll
      for (int j = 0; j < 2; ++j)
        cp[j * 16] = (_Float16)acc[i][j][r];
    }
  __syncthreads();
  #pragma unroll
  for (int v = 0; v < 4; ++v){
    int idx = v * 256 + tid;            // 1024 chunks of 8 f16
    int row = idx >> 4, cx = (idx & 15) * 8;
    if (r0 + row < n)
      *(uint4*)(C + (size_t)(r0 + row) * 256 + cb + cx)
        = *(const uint4*)(Csm + row * 136 + cx);
  }
}

// standalone GEMM (layer 0: A32 path, K=256; layer 1: A16 path, K=128)
__global__ __launch_bounds__(256) void gemm_mfma(
    const float* __restrict__ A32, const _Float16* __restrict__ A16,
    const _Float16* __restrict__ Bw, _Float16* __restrict__ C, int n, int K)
{
  __shared__ __align__(16) char smem[24576];
  gemm_body(smem, A32, A16, Bw, C, n, K, blockIdx.x, blockIdx.y);
}

// ---------------- pass 1: edge binning (standalone) --------------------------
// Bins edges by coarse bucket dst>>8 (196 buckets of 256 nodes): per block
// LDS-histogram its 2048 edges, ONE global cursor atomic per (block,bucket),
// then write packed (loc<<24|src) runs. Coalesced writes, no per-edge global
// atomics. Standalone (unfused from gemm0): binning is now cheap (~8 us), and
// fusing it cost a 444-block second round on the gemm (29% of a round with
// 71% of CUs idle) plus block-slot crowding.
__global__ __launch_bounds__(256) void pass1_kernel(
    const int* __restrict__ ei, int* __restrict__ bins, int* __restrict__ bcursor,
    int e_orig, int etot)
{
  __shared__ int lcnt[256];
  __shared__ int gbase[256];
  const int tid = threadIdx.x;
  lcnt[tid] = 0;
  __syncthreads();
  const int base = blockIdx.x * 2048 + tid;
  int pk[8], bk[8], lp[8];
  #pragma unroll
  for (int k = 0; k < 8; ++k){
    int i = base + k * 256;
    bk[k] = -1;
    if (i < etot){
      int src, dst;
      if (i < e_orig){ src = ei[i]; dst = ei[e_orig + i]; }
      else { src = i - e_orig; dst = src; }           // self loops
      bk[k] = dst >> 8;
      pk[k] = ((dst & 255) << 24) | src;              // src < 2^24
    }
  }
  #pragma unroll
  for (int k = 0; k < 8; ++k)
    if (bk[k] >= 0) lp[k] = atomicAdd(&lcnt[bk[k]], 1);
  __syncthreads();
  if (tid < 196 && lcnt[tid] > 0)
    gbase[tid] = atomicAdd(&bcursor[tid], lcnt[tid]);
  __syncthreads();
  #pragma unroll
  for (int k = 0; k < 8; ++k)
    if (bk[k] >= 0){
      int p = gbase[bk[k]] + lp[k];
      if (p < BCAP) bins[(size_t)bk[k] * BCAP + p] = pk[k];
    }
}

// ---------------- pass 2: per-bucket adjacency materialization ---------------
__global__ __launch_bounds__(256) void pass2_kernel(
    const int* __restrict__ bins, const int* __restrict__ bcursor,
    int* __restrict__ cnt, int* __restrict__ col2, int* __restrict__ hist, int n)
{
  __shared__ int stage[256 * CAP];   // 64 KB
  __shared__ int lcnt2[256];
  __shared__ int lh[64];
  const int b = blockIdx.x, tid = threadIdx.x;
  lcnt2[tid] = 0;
  if (tid < 64) lh[tid] = 0;
  __syncthreads();
  int ecnt = bcursor[b]; if (ecnt > BCAP) ecnt = BCAP;
  for (int i = tid; i < ecnt; i += 256){
    int v = bins[(size_t)b * BCAP + i];
    int src = v & 0xFFFFFF;
    int loc = ((unsigned)v) >> 24;
    int pos = atomicAdd(&lcnt2[loc], 1);
    if (pos < CAP) stage[loc * CAP + pos] = src;
  }
  __syncthreads();
  int node = b * 256 + tid;
  if (node < n){
    int d = lcnt2[tid];
    cnt[node] = d;
    int dc = d < 1 ? 1 : (d > CAP ? CAP : d);
    atomicAdd(&lh[dc - 1], 1);
  }
  __syncthreads();
  const uint4* sg = (const uint4*)stage;
  uint4* c4 = (uint4*)col2;
  for (int k2 = tid; k2 < 4096; k2 += 256){       // 4096 uint4 = 64 KB
    int nd = b * 256 + (k2 >> 4);
    if (nd < n) c4[(size_t)nd * 16 + (k2 & 15)] = sg[k2];
  }
  if (tid < 64 && lh[tid] > 0) atomicAdd(&hist[tid], lh[tid]);
}

// ---------------- GATv2 aggregation: 16-lane group per node, 8 ch/lane -------
// Degree-sorted perm (balanced waves) + 4-edge unroll + depth-8 rotating
// prefetch. VALU diet: (1) edge indices staged in LDS (slots>=deg prefilled
// with edge 0 -> clampless lane-uniform ds_read replaces cndmask+shfl chain);
// (2) packed-f16 logit via v_pk ops + v_dot2_f32_f16; (3) accv via fma_mix
// (f16 source, f32 accum). Same-wave LDS write->read needs no barrier.
__global__ __launch_bounds__(128) void agg_wave(
    const _Float16* __restrict__ XLR, const int* __restrict__ col2,
    const int* __restrict__ cnt, const int* __restrict__ perm,
    const float* __restrict__ att,
    const float* __restrict__ bias, _Float16* __restrict__ H16, int n)
{
  __shared__ int idxs[8][72];
  const int lane  = threadIdx.x & 63;
  const int g     = lane >> 4;          // group within wave (0..3)
  const int ll    = lane & 15;
  const int gbase = g << 4;
  const int nl    = ((threadIdx.x >> 6) << 2) + g;   // 0..7
  const int slot  = blockIdx.x * 8 + nl;
  if (slot >= n) return;
  const int node = perm[slot];
  int deg = cnt[node]; if (deg > CAP) deg = CAP;
  const int c0 = 8 * ll;

  h2 xrh[4], avh[4];
  {
    union { uint4 u; h2 v[4]; } xc;
    xc.u = *(const uint4*)(XLR + (size_t)node * 256 + 128 + c0);
    #pragma unroll
    for (int k = 0; k < 4; ++k) xrh[k] = xc.v[k];
    #pragma unroll
    for (int k = 0; k < 4; ++k)
      avh[k] = (h2){ (_Float16)att[c0 + 2*k], (_Float16)att[c0 + 2*k + 1] };
  }

  // stage edge indices: [0,deg) real, [deg,72) clamped to edge 0 (deg>=1)
  {
    int sq[4];
    #pragma unroll
    for (int q = 0; q < 4; ++q)
      sq[q] = (ll + 16*q < deg) ? col2[(size_t)node * CAP + ll + 16*q] : 0;
    int s0 = __shfl(sq[0], gbase);
    #pragma unroll
    for (int q = 0; q < 4; ++q)
      idxs[nl][ll + 16*q] = (ll + 16*q < deg) ? sq[q] : s0;
    if (ll < 8) idxs[nl][64 + ll] = s0;
  }
  const int* idxp = idxs[nl];

  float l = 0.f, accv[8];
  #pragma unroll
  for (int i = 0; i < 8; ++i) accv[i] = 0.f;

  uint4 x0, x1, x2, x3, x4, x5, x6, x7;
  {
    int e0 = idxp[0], e1 = idxp[1], e2 = idxp[2], e3 = idxp[3];
    int e4 = idxp[4], e5 = idxp[5], e6 = idxp[6], e7 = idxp[7];
    x0 = *(const uint4*)(XLR + (size_t)e0 * 256 + c0);
    x1 = *(const uint4*)(XLR + (size_t)e1 * 256 + c0);
    x2 = *(const uint4*)(XLR + (size_t)e2 * 256 + c0);
    x3 = *(const uint4*)(XLR + (size_t)e3 * 256 + c0);
    x4 = *(const uint4*)(XLR + (size_t)e4 * 256 + c0);
    x5 = *(const uint4*)(XLR + (size_t)e5 * 256 + c0);
    x6 = *(const uint4*)(XLR + (size_t)e6 * 256 + c0);
    x7 = *(const uint4*)(XLR + (size_t)e7 * 256 + c0);
  }

  int j = 0;
  for (; j + 4 <= deg; j += 4){
    uint4 y0 = x0, y1 = x1, y2 = x2, y3 = x3;
    x0 = x4; x1 = x5; x2 = x6; x3 = x7;
    int e8  = idxp[j + 8],  e9  = idxp[j + 9];
    int e10 = idxp[j + 10], e11 = idxp[j + 11];
    x4 = *(const uint4*)(XLR + (size_t)e8  * 256 + c0);
    x5 = *(const uint4*)(XLR + (size_t)e9  * 256 + c0);
    x6 = *(const uint4*)(XLR + (size_t)e10 * 256 + c0);
    x7 = *(const uint4*)(XLR + (size_t)e11 * 256 + c0);
    float p0 = edge_logit(y0, xrh, avh);
    float p1 = edge_logit(y1, xrh, avh);
    float p2 = edge_logit(y2, xrh, avh);
    float p3 = edge_logit(y3, xrh, avh);
    p0 += __shfl_xor(p0, 1);  p1 += __shfl_xor(p1, 1);
    p2 += __shfl_xor(p2, 1);  p3 += __shfl_xor(p3, 1);
    p0 += __shfl_xor(p0, 2);  p1 += __shfl_xor(p1, 2);
    p2 += __shfl_xor(p2, 2);  p3 += __shfl_xor(p3, 2);
    float w0 = __expf(p0), w1 = __expf(p1), w2 = __expf(p2), w3 = __expf(p3);
    l += (w0 + w1) + (w2 + w3);
    acc_edge(w0, y0, accv); acc_edge(w1, y1, accv);
    acc_edge(w2, y2, accv); acc_edge(w3, y3, accv);
  }
  // tail: up to 3 edges, already resident in x0..x2
  #pragma unroll
  for (int r = 0; r < 3; ++r){
    if (j + r < deg){
      uint4 xe = (r == 0) ? x0 : ((r == 1) ? x1 : x2);
      float p = edge_logit(xe, xrh, avh);
      p += __shfl_xor(p, 1);
      p += __shfl_xor(p, 2);
      float w = __expf(p);
      l += w;
      acc_edge(w, xe, accv);
    }
  }
  float inv = 1.f / l;
  union { h8 h; uint4 u; } o;
  #pragma unroll
  for (int i = 0; i < 8; ++i)
    o.h[i] = (_Float16)(accv[i] * inv + bias[c0 + i]);
  *(uint4*)(H16 + (size_t)node * 128 + c0) = o.u;
}

// ---------------- layer-1 aggregation fused with down_proj -------------------
// Same VALU-diet pipeline; h staged f32 in LDS; then each thread computes
// 2 (node, o) dot products against LDS-staged dW.
__global__ __launch_bounds__(256) void agg_down(
    const _Float16* __restrict__ XLR, const int* __restrict__ col2,
    const int* __restrict__ cnt, const int* __restrict__ perm,
    const float* __restrict__ att,
    const float* __restrict__ bias, const float* __restrict__ dW,
    const float* __restrict__ db, float* __restrict__ out, int n)
{
  __shared__ float dwb[32][129];
  __shared__ float hsm[16][128];
  __shared__ int idxs[16][72];
  for (int i = threadIdx.x; i < 32 * 128; i += 256)
    dwb[i >> 7][i & 127] = dW[i];

  const int lane  = threadIdx.x & 63;
  const int g     = lane >> 4;
  const int ll    = lane & 15;
  const int gbase = g << 4;
  const int nl    = ((threadIdx.x >> 6) << 2) + g;   // 0..15
  const int slot  = blockIdx.x * 16 + nl;
  const bool valid = slot < n;
  const int node = valid ? perm[slot] : 0;
  int deg = 0;
  if (valid){ deg = cnt[node]; if (deg > CAP) deg = CAP; }
  const int c0 = 8 * ll;

  h2 xrh[4], avh[4];
  {
    union { uint4 u; h2 v[4]; } xc;
    xc.u = (uint4){0u,0u,0u,0u};
    if (valid) xc.u = *(const uint4*)(XLR + (size_t)node * 256 + 128 + c0);
    #pragma unroll
    for (int k = 0; k < 4; ++k) xrh[k] = xc.v[k];
    #pragma unroll
    for (int k = 0; k < 4; ++k)
      avh[k] = (h2){ (_Float16)att[c0 + 2*k], (_Float16)att[c0 + 2*k + 1] };
  }

  {
    int sq[4];
    #pragma unroll
    for (int q = 0; q < 4; ++q)
      sq[q] = (valid && ll + 16*q < deg) ? col2[(size_t)node * CAP + ll + 16*q] : 0;
    int s0 = __shfl(sq[0], gbase);
    #pragma unroll
    for (int q = 0; q < 4; ++q)
      idxs[nl][ll + 16*q] = (ll + 16*q < deg) ? sq[q] : s0;
    if (ll < 8) idxs[nl][64 + ll] = s0;
  }
  const int* idxp = idxs[nl];

  float l = 0.f, accv[8];
  #pragma unroll
  for (int i = 0; i < 8; ++i) accv[i] = 0.f;

  uint4 x0, x1, x2, x3, x4, x5, x6, x7;
  {
    int e0 = idxp[0], e1 = idxp[1], e2 = idxp[2], e3 = idxp[3];
    int e4 = idxp[4], e5 = idxp[5], e6 = idxp[6], e7 = idxp[7];
    x0 = *(const uint4*)(XLR + (size_t)e0 * 256 + c0);
    x1 = *(const uint4*)(XLR + (size_t)e1 * 256 + c0);
    x2 = *(const uint4*)(XLR + (size_t)e2 * 256 + c0);
    x3 = *(const uint4*)(XLR + (size_t)e3 * 256 + c0);
    x4 = *(const uint4*)(XLR + (size_t)e4 * 256 + c0);
    x5 = *(const uint4*)(XLR + (size_t)e5 * 256 + c0);
    x6 = *(const uint4*)(XLR + (size_t)e6 * 256 + c0);
    x7 = *(const uint4*)(XLR + (size_t)e7 * 256 + c0);
  }

  int j = 0;
  for (; j + 4 <= deg; j += 4){
    uint4 y0 = x0, y1 = x1, y2 = x2, y3 = x3;
    x0 = x4; x1 = x5; x2 = x6; x3 = x7;
    int e8  = idxp[j + 8],  e9  = idxp[j + 9];
    int e10 = idxp[j + 10], e11 = idxp[j + 11];
    x4 = *(const uint4*)(XLR + (size_t)e8  * 256 + c0);
    x5 = *(const uint4*)(XLR + (size_t)e9  * 256 + c0);
    x6 = *(const uint4*)(XLR + (size_t)e10 * 256 + c0);
    x7 = *(const uint4*)(XLR + (size_t)e11 * 256 + c0);
    float p0 = edge_logit(y0, xrh, avh);
    float p1 = edge_logit(y1, xrh, avh);
    float p2 = edge_logit(y2, xrh, avh);
    float p3 = edge_logit(y3, xrh, avh);
    p0 += __shfl_xor(p0, 1);  p1 += __shfl_xor(p1, 1);
    p2 += __shfl_xor(p2, 1);  p3 += __shfl_xor(p3, 1);
    p0 += __shfl_xor(p0, 2);  p1 += __shfl_xor(p1, 2);
    p2 += __shfl_xor(p2, 2);  p3 += __shfl_xor(p3, 2);
    float w0 = __expf(p0), w1 = __expf(p1), w2 = __expf(p2), w3 = __expf(p3);
    l += (w0 + w1) + (w2 + w3);
    acc_edge(w0, y0, accv); acc_edge(w1, y1, accv);
    acc_edge(w2, y2, accv); acc_edge(w3, y3, accv);
  }
  #pragma unroll
  for (int r = 0; r < 3; ++r){
    if (j + r < deg){
      uint4 xe = (r == 0) ? x0 : ((r == 1) ? x1 : x2);
      float p = edge_logit(xe, xrh, avh);
      p += __shfl_xor(p, 1);
      p += __shfl_xor(p, 2);
      float w = __expf(p);
      l += w;
      acc_edge(w, xe, accv);
    }
  }
  {
    float inv = (deg > 0) ? 1.f / l : 0.f;
    #pragma unroll
    for (int i = 0; i < 8; ++i)
      hsm[nl][c0 + i] = accv[i] * inv + bias[c0 + i];
  }
  __syncthreads();

  // ---- down phase: 512 outputs over 256 threads (2 each) ----
  const int o = threadIdx.x & 31;
  #pragma unroll
  for (int h2i = 0; h2i < 2; ++h2i){
    int nl2 = (threadIdx.x >> 5) + h2i * 8;
    int slot2 = blockIdx.x * 16 + nl2;
    float sum = 0.f;
    #pragma unroll 8
    for (int k = 0; k < 128; ++k)
      sum += hsm[nl2][k] * dwb[o][k];
    if (slot2 < n)
      out[(size_t)perm[slot2] * 32 + o] = sum + db[o];
  }
}

extern "C" void kernel_launch(void* const* d_in, const int* in_sizes, int n_in,
                              void* d_out, int out_size, void* d_ws, size_t ws_size,
                              hipStream_t stream) {
  const float* x     = (const float*)d_in[0];
  const int*   ei    = (const int*)  d_in[1];
  const float* Wl0   = (const float*)d_in[2];
  const float* Wr0   = (const float*)d_in[3];
  const float* att0  = (const float*)d_in[4];
  const float* b0    = (const float*)d_in[5];
  const float* Wl1   = (const float*)d_in[6];
  const float* Wr1   = (const float*)d_in[7];
  const float* att1  = (const float*)d_in[8];
  const float* b1    = (const float*)d_in[9];
  const float* dW    = (const float*)d_in[10];
  const float* db    = (const float*)d_in[11];
  float* out = (float*)d_out;

  const int n    = in_sizes[0] / 256;      // 50000
  const int e    = in_sizes[1] / 2;        // 800000
  const int etot = e + n;

  // workspace layout
  _Float16* XLR16 = (_Float16*)d_ws;                    // n*256 f16
  _Float16* H16   = XLR16 + (size_t)n * 256;            // n*128 f16
  int* col2 = (int*)(H16 + (size_t)n * 128);            // n*CAP
  int* cnt  = col2 + (size_t)n * CAP;                   // n
  int* hist    = cnt + n;                               // 64
  int* cursor  = hist + 64;                             // 64
  int* bcursor = cursor + 64;                           // 256 (196 used)
  int* perm    = bcursor + 256;                         // n
  _Float16* B0h = (_Float16*)(perm + ((n + 3) & ~3));   // 256*256 f16
  _Float16* B1h = B0h + 65536;                          // 256*128 f16
  int* bins = (int*)H16;    // 196*BCAP ints = 4.8 MB, aliases H16 (dead till agg_wave)

  // zero cnt + hist + cursor + bcursor in one shot (contiguous)
  (void)hipMemsetAsync(cnt, 0, ((size_t)n + 384) * sizeof(int), stream);
  convw_kernel<<<96, 256, 0, stream>>>(Wl0, Wr0, Wl1, Wr1, B0h, B1h);

  // pass1 binning (standalone, full occupancy)
  const int NP = (etot + 2047) / 2048;          // 416
  pass1_kernel<<<NP, 256, 0, stream>>>(ei, bins, bcursor, e, etot);

  // layer-0 GEMM (standalone; 1564 blocks at 6/CU -> 2% tail)
  dim3 ggrid(2, (n + 63) / 64);
  gemm_mfma<<<ggrid, 256, 0, stream>>>(x, nullptr, B0h, XLR16, n, 256);

  const int NB2 = (n + 255) / 256;              // 196
  pass2_kernel<<<NB2, 256, 0, stream>>>(bins, bcursor, cnt, col2, hist, n);
  scatter_kernel<<<(n + 255) / 256, 256, 0, stream>>>(cnt, hist, cursor, perm, n);

  agg_wave<<<(n + 7) / 8, 128, 0, stream>>>(XLR16, col2, cnt, perm, att0, b0, H16, n);
  // layer 1 (A = H16 in f16)
  gemm_mfma<<<ggrid, 256, 0, stream>>>(nullptr, H16, B1h, XLR16, n, 128);
  // layer-1 agg + down proj fused
  agg_down<<<(n + 15) / 16, 256, 0, stream>>>(XLR16, col2, cnt, perm, att1, b1, dW, db, out, n);
}

// Round 12
// 270.656 us; speedup vs baseline: 1.1137x; 1.0659x over previous
//
#include <hip/hip_runtime.h>

#define CAP 64
#define BCAP 6144   // per-bucket edge capacity (mean 4352 + 27 sigma)

typedef _Float16 h8 __attribute__((ext_vector_type(8)));
typedef _Float16 h4 __attribute__((ext_vector_type(4)));
typedef _Float16 h2 __attribute__((ext_vector_type(2)));
typedef float f32x4 __attribute__((ext_vector_type(4)));

__device__ __forceinline__ uint4 pack8(float4 a, float4 b){
  union { h8 h; uint4 u; } cv;
  cv.h = (h8){ (_Float16)a.x, (_Float16)a.y, (_Float16)a.z, (_Float16)a.w,
               (_Float16)b.x, (_Float16)b.y, (_Float16)b.z, (_Float16)b.w };
  return cv.u;
}

// packed-f16 logit partial: sum_k dot2(lrelu(c2k + xr2k), att2k), f32 accum
__device__ __forceinline__ float edge_logit(uint4 xu, const h2* xrh, const h2* avh){
  union { uint4 u; h2 v[4]; } cu; cu.u = xu;
  const h2 z2 = { (_Float16)0.f, (_Float16)0.f };
  const h2 sl = { (_Float16)0.2f, (_Float16)0.2f };
  float p = 0.f;
  #pragma unroll
  for (int k = 0; k < 4; ++k){
    h2 t  = cu.v[k] + xrh[k];
    h2 hi = __builtin_elementwise_max(t, z2);
    h2 lo = __builtin_elementwise_min(t, z2);
    h2 lr = hi + lo * sl;
    p = __builtin_amdgcn_fdot2(lr, avh[k], p, false);
  }
  return p;
}
// accv += w * c (f16 source, f32 accum; fma_mix pattern)
__device__ __forceinline__ void acc_edge(float w, uint4 xu, float* accv){
  union { uint4 u; _Float16 e[8]; } ce; ce.u = xu;
  #pragma unroll
  for (int i = 0; i < 8; ++i) accv[i] += w * (float)ce.e[i];
}

// XCD-pairing tile map: the two column-half blocks (bx=0/1, same by) are
// placed 8 apart in dispatch order -> same XCD residue (round-robin block->XCD)
// and temporally close -> the shared 64KB A-panel stays in that XCD's L2.
// Bijective for any nby (tail handled with rem = nby - (nby & ~7)).
__device__ __forceinline__ void tile_map(int gi, int nby, int& bx, int& by){
  const int nby8 = nby & ~7;
  if (gi < 2 * nby8){
    int g8 = gi >> 4, r = gi & 15;
    bx = r >> 3;
    by = g8 * 8 + (r & 7);
  } else {
    int t = gi - 2 * nby8, rem = nby - nby8;
    bx = t / rem;
    by = nby8 + t % rem;
  }
}

// ---------------- W pack: B0h[256x256] = [Wl0; Wr0], B1h[256x128] = [Wl1; Wr1]
__global__ void convw_kernel(const float* __restrict__ Wl0, const float* __restrict__ Wr0,
                             const float* __restrict__ Wl1, const float* __restrict__ Wr1,
                             _Float16* __restrict__ B0h, _Float16* __restrict__ B1h){
  int t = blockIdx.x * blockDim.x + threadIdx.x;   // float4 units, 24576 total
  const float* s; _Float16* d; int off;
  if (t < 8192)      { s = Wl0; d = B0h;          off = t; }
  else if (t < 16384){ s = Wr0; d = B0h + 32768;  off = t - 8192; }
  else if (t < 20480){ s = Wl1; d = B1h;          off = t - 16384; }
  else               { s = Wr1; d = B1h + 16384;  off = t - 20480; }
  float4 f = ((const float4*)s)[off];
  h4 h = { (_Float16)f.x, (_Float16)f.y, (_Float16)f.z, (_Float16)f.w };
  *(h4*)(d + 4 * (size_t)off) = h;
}

// counting-sort scatter, LDS-aggregated: local rank via LDS atomics, one
// global cursor atomic per (block, bucket). Within-bucket order arbitrary.
__global__ void scatter_kernel(const int* __restrict__ cnt, const int* __restrict__ hist,
                               int* __restrict__ cursor, int* __restrict__ perm, int n){
  __shared__ int base[64];
  __shared__ int lh[64];
  __shared__ int lbase[64];
  __shared__ int ht[64];
  if (threadIdx.x < 64){
    lh[threadIdx.x] = 0;
    ht[threadIdx.x] = hist[threadIdx.x];
  }
  __syncthreads();
  if (threadIdx.x == 0){
    int acc = 0;
    for (int d = 63; d >= 0; --d){ base[d] = acc; acc += ht[d]; }  // descending deg
  }
  int i = blockIdx.x * blockDim.x + threadIdx.x;
  int d = 1, lr = 0;
  if (i < n){
    d = cnt[i]; d = (d < 1) ? 1 : (d > CAP ? CAP : d);
    lr = atomicAdd(&lh[d - 1], 1);
  }
  __syncthreads();
  if (threadIdx.x < 64 && lh[threadIdx.x] > 0)
    lbase[threadIdx.x] = atomicAdd(&cursor[threadIdx.x], lh[threadIdx.x]);
  __syncthreads();
  if (i < n)
    perm[base[d - 1] + lbase[d - 1] + lr] = i;
}

// ---------------- f16 MFMA GEMM body, tile 64 rows x 128 cols ----------------
// 4 waves: wave wx -> cols wx*32..+31 (4x2 MFMA tiles of 16x16x32_f16),
// BK=64, register-prefetch pipeline. LDS rows at exact 128 B with XOR swizzle
// (byte ^= (row&7)<<4): 24576 B total -> 6 blocks/CU. Epilogue restages f16 C
// tile in LDS. A read as f32 (layer 0, fused convert) or f16 (layer 1).
__device__ __forceinline__ void gemm_body(
    char* smem, const float* __restrict__ A32, const _Float16* __restrict__ A16,
    const _Float16* __restrict__ Bw, _Float16* __restrict__ C, int n, int K,
    int bx, int by)
{
  char* Abase = smem;            // 64 rows x 128 B (swizzled)
  char* Bbase = smem + 8192;     // 128 rows x 128 B (swizzled)

  const int tid  = threadIdx.x;
  const int lane = tid & 63;
  const int wx   = tid >> 6;
  const int r0   = by * 64;
  const int cb   = bx * 128;
  const int m16  = lane & 15, quad = lane >> 4;

  f32x4 acc[4][2];
  #pragma unroll
  for (int i = 0; i < 4; ++i)
    #pragma unroll
    for (int j = 0; j < 2; ++j)
      acc[i][j] = (f32x4){0.f, 0.f, 0.f, 0.f};

  const int srow = tid >> 2;        // 0..63
  const int kq   = (tid & 3) << 4;  // 0,16,32,48 (elements)
  const int kb   = kq * 2;          // bytes within row
  const int swz  = (srow & 7) << 4; // write-side row swizzle

  uint4 ra[2], rb[2][2];
  const uint4 z = {0u, 0u, 0u, 0u};

  if (r0 + srow < n){
    if (A32){
      const float* p = A32 + (size_t)(r0 + srow) * K + kq;
      ra[0] = pack8(*(const float4*)(p),     *(const float4*)(p + 4));
      ra[1] = pack8(*(const float4*)(p + 8), *(const float4*)(p + 12));
    } else {
      const _Float16* p = A16 + (size_t)(r0 + srow) * K + kq;
      ra[0] = *(const uint4*)(p);
      ra[1] = *(const uint4*)(p + 8);
    }
  } else { ra[0] = z; ra[1] = z; }
  #pragma unroll
  for (int v = 0; v < 2; ++v){
    const _Float16* p = Bw + (size_t)(cb + v * 64 + srow) * K + kq;
    rb[v][0] = *(const uint4*)(p);
    rb[v][1] = *(const uint4*)(p + 8);
  }

  const int nt = K >> 6;
  for (int t = 0; t < nt; ++t){
    *(uint4*)(Abase + srow * 128 + (kb ^ swz))        = ra[0];
    *(uint4*)(Abase + srow * 128 + ((kb + 16) ^ swz)) = ra[1];
    #pragma unroll
    for (int v = 0; v < 2; ++v){
      *(uint4*)(Bbase + (v * 64 + srow) * 128 + (kb ^ swz))        = rb[v][0];
      *(uint4*)(Bbase + (v * 64 + srow) * 128 + ((kb + 16) ^ swz)) = rb[v][1];
    }
    __syncthreads();
    if (t + 1 < nt){
      int kt = (t + 1) << 6;
      if (r0 + srow < n){
        if (A32){
          const float* p = A32 + (size_t)(r0 + srow) * K + kt + kq;
          ra[0] = pack8(*(const float4*)(p),     *(const float4*)(p + 4));
          ra[1] = pack8(*(const float4*)(p + 8), *(const float4*)(p + 12));
        } else {
          const _Float16* p = A16 + (size_t)(r0 + srow) * K + kt + kq;
          ra[0] = *(const uint4*)(p);
          ra[1] = *(const uint4*)(p + 8);
        }
      }
      #pragma unroll
      for (int v = 0; v < 2; ++v){
        const _Float16* p = Bw + (size_t)(cb + v * 64 + srow) * K + kt + kq;
        rb[v][0] = *(const uint4*)(p);
        rb[v][1] = *(const uint4*)(p + 8);
      }
    }
    const int swr = (m16 & 7) << 4;   // read-side row swizzle
    #pragma unroll
    for (int ks = 0; ks < 2; ++ks){
      const int k0 = ks * 32 + quad * 8;
      const int cbyte = (k0 * 2) ^ swr;
      h8 a[4], b[2];
      #pragma unroll
      for (int i = 0; i < 4; ++i)
        a[i] = *(const h8*)(Abase + (i * 16 + m16) * 128 + cbyte);
      #pragma unroll
      for (int j = 0; j < 2; ++j)
        b[j] = *(const h8*)(Bbase + (wx * 32 + j * 16 + m16) * 128 + cbyte);
      #pragma unroll
      for (int i = 0; i < 4; ++i)
        #pragma unroll
        for (int j = 0; j < 2; ++j)
          acc[i][j] = __builtin_amdgcn_mfma_f32_16x16x32_f16(a[i], b[j], acc[i][j], 0, 0, 0);
    }
    __syncthreads();
  }

  _Float16* Csm = (_Float16*)smem;
  #pragma unroll
  for (int i = 0; i < 4; ++i)
    #pragma unroll
    for (int r = 0; r < 4; ++r){
      int lrow = i * 16 + quad * 4 + r;
      _Float16* cp = Csm + lrow * 136 + wx * 32 + m16;
      #pragma unroll
      for (int j = 0; j < 2; ++j)
        cp[j * 16] = (_Float16)acc[i][j][r];
    }
  __syncthreads();
  #pragma unroll
  for (int v = 0; v < 4; ++v){
    int idx = v * 256 + tid;            // 1024 chunks of 8 f16
    int row = idx >> 4, cx = (idx & 15) * 8;
    if (r0 + row < n)
      *(uint4*)(C + (size_t)(r0 + row) * 256 + cb + cx)
        = *(const uint4*)(Csm + row * 136 + cx);
  }
}

// standalone GEMM (layer 1), 1D grid with XCD-pairing tile map
__global__ __launch_bounds__(256) void gemm_mfma(
    const float* __restrict__ A32, const _Float16* __restrict__ A16,
    const _Float16* __restrict__ Bw, _Float16* __restrict__ C, int n, int K)
{
  __shared__ __align__(16) char smem[24576];
  const int nby = (n + 63) / 64;
  int bx, by;
  tile_map(blockIdx.x, nby, bx, by);
  gemm_body(smem, A32, A16, Bw, C, n, K, bx, by);
}

// ---------------- fused: layer-0 GEMM  ∥  edge binning (pass 1) --------------
// pass1 bins edges by coarse bucket dst>>8 (196 buckets of 256 nodes): per
// block LDS-histogram its 2048 edges, ONE global cursor atomic per
// (block,bucket), then write packed (loc<<24|src) runs. Coalesced writes, no
// per-edge global atomics. pass1 blocks dispatched first, gemm blocks fill
// behind with the XCD-pairing tile map (NP = 416 ≡ 0 mod 8, so gi-residues
// carry through to block-residues).
__global__ __launch_bounds__(256) void gemm_pass1(
    const float* __restrict__ A32, const _Float16* __restrict__ Bw,
    _Float16* __restrict__ C, int n,
    const int* __restrict__ ei, int* __restrict__ bins, int* __restrict__ bcursor,
    int e_orig, int etot, int NP)
{
  __shared__ __align__(16) char smem[24576];
  const int lin = blockIdx.x;
  if (lin >= NP){
    const int nby = (n + 63) / 64;
    int bx, by;
    tile_map(lin - NP, nby, bx, by);
    gemm_body(smem, A32, nullptr, Bw, C, n, 256, bx, by);
  } else {
    int* lcnt  = (int*)smem;                 // 196
    int* gbase = lcnt + 256;                 // 196
    const int tid = threadIdx.x;
    if (tid < 196) lcnt[tid] = 0;
    __syncthreads();
    const int base = lin * 2048 + tid;
    int pk[8], bk[8], lp[8];
    #pragma unroll
    for (int k = 0; k < 8; ++k){
      int i = base + k * 256;
      bk[k] = -1;
      if (i < etot){
        int src, dst;
        if (i < e_orig){ src = ei[i]; dst = ei[e_orig + i]; }
        else { src = i - e_orig; dst = src; }           // self loops
        bk[k] = dst >> 8;
        pk[k] = ((dst & 255) << 24) | src;              // src < 2^24
      }
    }
    #pragma unroll
    for (int k = 0; k < 8; ++k)
      if (bk[k] >= 0) lp[k] = atomicAdd(&lcnt[bk[k]], 1);
    __syncthreads();
    if (tid < 196 && lcnt[tid] > 0)
      gbase[tid] = atomicAdd(&bcursor[tid], lcnt[tid]);
    __syncthreads();
    #pragma unroll
    for (int k = 0; k < 8; ++k)
      if (bk[k] >= 0){
        int p = gbase[bk[k]] + lp[k];
        if (p < BCAP) bins[(size_t)bk[k] * BCAP + p] = pk[k];
      }
  }
}

// ---------------- pass 2: per-bucket adjacency materialization ---------------
__global__ __launch_bounds__(256) void pass2_kernel(
    const int* __restrict__ bins, const int* __restrict__ bcursor,
    int* __restrict__ cnt, int* __restrict__ col2, int* __restrict__ hist, int n)
{
  __shared__ int stage[256 * CAP];   // 64 KB
  __shared__ int lcnt2[256];
  __shared__ int lh[64];
  const int b = blockIdx.x, tid = threadIdx.x;
  lcnt2[tid] = 0;
  if (tid < 64) lh[tid] = 0;
  __syncthreads();
  int ecnt = bcursor[b]; if (ecnt > BCAP) ecnt = BCAP;
  for (int i = tid; i < ecnt; i += 256){
    int v = bins[(size_t)b * BCAP + i];
    int src = v & 0xFFFFFF;
    int loc = ((unsigned)v) >> 24;
    int pos = atomicAdd(&lcnt2[loc], 1);
    if (pos < CAP) stage[loc * CAP + pos] = src;
  }
  __syncthreads();
  int node = b * 256 + tid;
  if (node < n){
    int d = lcnt2[tid];
    cnt[node] = d;
    int dc = d < 1 ? 1 : (d > CAP ? CAP : d);
    atomicAdd(&lh[dc - 1], 1);
  }
  __syncthreads();
  const uint4* sg = (const uint4*)stage;
  uint4* c4 = (uint4*)col2;
  for (int k2 = tid; k2 < 4096; k2 += 256){       // 4096 uint4 = 64 KB
    int nd = b * 256 + (k2 >> 4);
    if (nd < n) c4[(size_t)nd * 16 + (k2 & 15)] = sg[k2];
  }
  if (tid < 64 && lh[tid] > 0) atomicAdd(&hist[tid], lh[tid]);
}

// ---------------- GATv2 aggregation: 16-lane group per node, 8 ch/lane -------
// Degree-sorted perm (balanced waves) + 4-edge unroll + depth-8 rotating
// prefetch. VALU diet: (1) edge indices staged in LDS (slots>=deg prefilled
// with edge 0 -> clampless lane-uniform ds_read replaces cndmask+shfl chain);
// (2) packed-f16 logit via v_pk ops + v_dot2_f32_f16; (3) accv via fma_mix
// (f16 source, f32 accum). Same-wave LDS write->read needs no barrier.
__global__ __launch_bounds__(128) void agg_wave(
    const _Float16* __restrict__ XLR, const int* __restrict__ col2,
    const int* __restrict__ cnt, const int* __restrict__ perm,
    const float* __restrict__ att,
    const float* __restrict__ bias, _Float16* __restrict__ H16, int n)
{
  __shared__ int idxs[8][72];
  const int lane  = threadIdx.x & 63;
  const int g     = lane >> 4;          // group within wave (0..3)
  const int ll    = lane & 15;
  const int gbase = g << 4;
  const int nl    = ((threadIdx.x >> 6) << 2) + g;   // 0..7
  const int slot  = blockIdx.x * 8 + nl;
  if (slot >= n) return;
  const int node = perm[slot];
  int deg = cnt[node]; if (deg > CAP) deg = CAP;
  const int c0 = 8 * ll;

  h2 xrh[4], avh[4];
  {
    union { uint4 u; h2 v[4]; } xc;
    xc.u = *(const uint4*)(XLR + (size_t)node * 256 + 128 + c0);
    #pragma unroll
    for (int k = 0; k < 4; ++k) xrh[k] = xc.v[k];
    #pragma unroll
    for (int k = 0; k < 4; ++k)
      avh[k] = (h2){ (_Float16)att[c0 + 2*k], (_Float16)att[c0 + 2*k + 1] };
  }

  // stage edge indices: [0,deg) real, [deg,72) clamped to edge 0 (deg>=1)
  {
    int sq[4];
    #pragma unroll
    for (int q = 0; q < 4; ++q)
      sq[q] = (ll + 16*q < deg) ? col2[(size_t)node * CAP + ll + 16*q] : 0;
    int s0 = __shfl(sq[0], gbase);
    #pragma unroll
    for (int q = 0; q < 4; ++q)
      idxs[nl][ll + 16*q] = (ll + 16*q < deg) ? sq[q] : s0;
    if (ll < 8) idxs[nl][64 + ll] = s0;
  }
  const int* idxp = idxs[nl];

  float l = 0.f, accv[8];
  #pragma unroll
  for (int i = 0; i < 8; ++i) accv[i] = 0.f;

  uint4 x0, x1, x2, x3, x4, x5, x6, x7;
  {
    int e0 = idxp[0], e1 = idxp[1], e2 = idxp[2], e3 = idxp[3];
    int e4 = idxp[4], e5 = idxp[5], e6 = idxp[6], e7 = idxp[7];
    x0 = *(const uint4*)(XLR + (size_t)e0 * 256 + c0);
    x1 = *(const uint4*)(XLR + (size_t)e1 * 256 + c0);
    x2 = *(const uint4*)(XLR + (size_t)e2 * 256 + c0);
    x3 = *(const uint4*)(XLR + (size_t)e3 * 256 + c0);
    x4 = *(const uint4*)(XLR + (size_t)e4 * 256 + c0);
    x5 = *(const uint4*)(XLR + (size_t)e5 * 256 + c0);
    x6 = *(const uint4*)(XLR + (size_t)e6 * 256 + c0);
    x7 = *(const uint4*)(XLR + (size_t)e7 * 256 + c0);
  }

  int j = 0;
  for (; j + 4 <= deg; j += 4){
    uint4 y0 = x0, y1 = x1, y2 = x2, y3 = x3;
    x0 = x4; x1 = x5; x2 = x6; x3 = x7;
    int e8  = idxp[j + 8],  e9  = idxp[j + 9];
    int e10 = idxp[j + 10], e11 = idxp[j + 11];
    x4 = *(const uint4*)(XLR + (size_t)e8  * 256 + c0);
    x5 = *(const uint4*)(XLR + (size_t)e9  * 256 + c0);
    x6 = *(const uint4*)(XLR + (size_t)e10 * 256 + c0);
    x7 = *(const uint4*)(XLR + (size_t)e11 * 256 + c0);
    float p0 = edge_logit(y0, xrh, avh);
    float p1 = edge_logit(y1, xrh, avh);
    float p2 = edge_logit(y2, xrh, avh);
    float p3 = edge_logit(y3, xrh, avh);
    p0 += __shfl_xor(p0, 1);  p1 += __shfl_xor(p1, 1);
    p2 += __shfl_xor(p2, 1);  p3 += __shfl_xor(p3, 1);
    p0 += __shfl_xor(p0, 2);  p1 += __shfl_xor(p1, 2);
    p2 += __shfl_xor(p2, 2);  p3 += __shfl_xor(p3, 2);
    float w0 = __expf(p0), w1 = __expf(p1), w2 = __expf(p2), w3 = __expf(p3);
    l += (w0 + w1) + (w2 + w3);
    acc_edge(w0, y0, accv); acc_edge(w1, y1, accv);
    acc_edge(w2, y2, accv); acc_edge(w3, y3, accv);
  }
  // tail: up to 3 edges, already resident in x0..x2
  #pragma unroll
  for (int r = 0; r < 3; ++r){
    if (j + r < deg){
      uint4 xe = (r == 0) ? x0 : ((r == 1) ? x1 : x2);
      float p = edge_logit(xe, xrh, avh);
      p += __shfl_xor(p, 1);
      p += __shfl_xor(p, 2);
      float w = __expf(p);
      l += w;
      acc_edge(w, xe, accv);
    }
  }
  float inv = 1.f / l;
  union { h8 h; uint4 u; } o;
  #pragma unroll
  for (int i = 0; i < 8; ++i)
    o.h[i] = (_Float16)(accv[i] * inv + bias[c0 + i]);
  *(uint4*)(H16 + (size_t)node * 128 + c0) = o.u;
}

// ---------------- layer-1 aggregation fused with down_proj -------------------
// Same VALU-diet pipeline; h staged f32 in LDS; then each thread computes
// 2 (node, o) dot products against LDS-staged dW.
__global__ __launch_bounds__(256) void agg_down(
    const _Float16* __restrict__ XLR, const int* __restrict__ col2,
    const int* __restrict__ cnt, const int* __restrict__ perm,
    const float* __restrict__ att,
    const float* __restrict__ bias, const float* __restrict__ dW,
    const float* __restrict__ db, float* __restrict__ out, int n)
{
  __shared__ float dwb[32][129];
  __shared__ float hsm[16][128];
  __shared__ int idxs[16][72];
  for (int i = threadIdx.x; i < 32 * 128; i += 256)
    dwb[i >> 7][i & 127] = dW[i];

  const int lane  = threadIdx.x & 63;
  const int g     = lane >> 4;
  const int ll    = lane & 15;
  const int gbase = g << 4;
  const int nl    = ((threadIdx.x >> 6) << 2) + g;   // 0..15
  const int slot  = blockIdx.x * 16 + nl;
  const bool valid = slot < n;
  const int node = valid ? perm[slot] : 0;
  int deg = 0;
  if (valid){ deg = cnt[node]; if (deg > CAP) deg = CAP; }
  const int c0 = 8 * ll;

  h2 xrh[4], avh[4];
  {
    union { uint4 u; h2 v[4]; } xc;
    xc.u = (uint4){0u,0u,0u,0u};
    if (valid) xc.u = *(const uint4*)(XLR + (size_t)node * 256 + 128 + c0);
    #pragma unroll
    for (int k = 0; k < 4; ++k) xrh[k] = xc.v[k];
    #pragma unroll
    for (int k = 0; k < 4; ++k)
      avh[k] = (h2){ (_Float16)att[c0 + 2*k], (_Float16)att[c0 + 2*k + 1] };
  }

  {
    int sq[4];
    #pragma unroll
    for (int q = 0; q < 4; ++q)
      sq[q] = (valid && ll + 16*q < deg) ? col2[(size_t)node * CAP + ll + 16*q] : 0;
    int s0 = __shfl(sq[0], gbase);
    #pragma unroll
    for (int q = 0; q < 4; ++q)
      idxs[nl][ll + 16*q] = (ll + 16*q < deg) ? sq[q] : s0;
    if (ll < 8) idxs[nl][64 + ll] = s0;
  }
  const int* idxp = idxs[nl];

  float l = 0.f, accv[8];
  #pragma unroll
  for (int i = 0; i < 8; ++i) accv[i] = 0.f;

  uint4 x0, x1, x2, x3, x4, x5, x6, x7;
  {
    int e0 = idxp[0], e1 = idxp[1], e2 = idxp[2], e3 = idxp[3];
    int e4 = idxp[4], e5 = idxp[5], e6 = idxp[6], e7 = idxp[7];
    x0 = *(const uint4*)(XLR + (size_t)e0 * 256 + c0);
    x1 = *(const uint4*)(XLR + (size_t)e1 * 256 + c0);
    x2 = *(const uint4*)(XLR + (size_t)e2 * 256 + c0);
    x3 = *(const uint4*)(XLR + (size_t)e3 * 256 + c0);
    x4 = *(const uint4*)(XLR + (size_t)e4 * 256 + c0);
    x5 = *(const uint4*)(XLR + (size_t)e5 * 256 + c0);
    x6 = *(const uint4*)(XLR + (size_t)e6 * 256 + c0);
    x7 = *(const uint4*)(XLR + (size_t)e7 * 256 + c0);
  }

  int j = 0;
  for (; j + 4 <= deg; j += 4){
    uint4 y0 = x0, y1 = x1, y2 = x2, y3 = x3;
    x0 = x4; x1 = x5; x2 = x6; x3 = x7;
    int e8  = idxp[j + 8],  e9  = idxp[j + 9];
    int e10 = idxp[j + 10], e11 = idxp[j + 11];
    x4 = *(const uint4*)(XLR + (size_t)e8  * 256 + c0);
    x5 = *(const uint4*)(XLR + (size_t)e9  * 256 + c0);
    x6 = *(const uint4*)(XLR + (size_t)e10 * 256 + c0);
    x7 = *(const uint4*)(XLR + (size_t)e11 * 256 + c0);
    float p0 = edge_logit(y0, xrh, avh);
    float p1 = edge_logit(y1, xrh, avh);
    float p2 = edge_logit(y2, xrh, avh);
    float p3 = edge_logit(y3, xrh, avh);
    p0 += __shfl_xor(p0, 1);  p1 += __shfl_xor(p1, 1);
    p2 += __shfl_xor(p2, 1);  p3 += __shfl_xor(p3, 1);
    p0 += __shfl_xor(p0, 2);  p1 += __shfl_xor(p1, 2);
    p2 += __shfl_xor(p2, 2);  p3 += __shfl_xor(p3, 2);
    float w0 = __expf(p0), w1 = __expf(p1), w2 = __expf(p2), w3 = __expf(p3);
    l += (w0 + w1) + (w2 + w3);
    acc_edge(w0, y0, accv); acc_edge(w1, y1, accv);
    acc_edge(w2, y2, accv); acc_edge(w3, y3, accv);
  }
  #pragma unroll
  for (int r = 0; r < 3; ++r){
    if (j + r < deg){
      uint4 xe = (r == 0) ? x0 : ((r == 1) ? x1 : x2);
      float p = edge_logit(xe, xrh, avh);
      p += __shfl_xor(p, 1);
      p += __shfl_xor(p, 2);
      float w = __expf(p);
      l += w;
      acc_edge(w, xe, accv);
    }
  }
  {
    float inv = (deg > 0) ? 1.f / l : 0.f;
    #pragma unroll
    for (int i = 0; i < 8; ++i)
      hsm[nl][c0 + i] = accv[i] * inv + bias[c0 + i];
  }
  __syncthreads();

  // ---- down phase: 512 outputs over 256 threads (2 each) ----
  const int o = threadIdx.x & 31;
  #pragma unroll
  for (int h2i = 0; h2i < 2; ++h2i){
    int nl2 = (threadIdx.x >> 5) + h2i * 8;
    int slot2 = blockIdx.x * 16 + nl2;
    float sum = 0.f;
    #pragma unroll 8
    for (int k = 0; k < 128; ++k)
      sum += hsm[nl2][k] * dwb[o][k];
    if (slot2 < n)
      out[(size_t)perm[slot2] * 32 + o] = sum + db[o];
  }
}

extern "C" void kernel_launch(void* const* d_in, const int* in_sizes, int n_in,
                              void* d_out, int out_size, void* d_ws, size_t ws_size,
                              hipStream_t stream) {
  const float* x     = (const float*)d_in[0];
  const int*   ei    = (const int*)  d_in[1];
  const float* Wl0   = (const float*)d_in[2];
  const float* Wr0   = (const float*)d_in[3];
  const float* att0  = (const float*)d_in[4];
  const float* b0    = (const float*)d_in[5];
  const float* Wl1   = (const float*)d_in[6];
  const float* Wr1   = (const float*)d_in[7];
  const float* att1  = (const float*)d_in[8];
  const float* b1    = (const float*)d_in[9];
  const float* dW    = (const float*)d_in[10];
  const float* db    = (const float*)d_in[11];
  float* out = (float*)d_out;

  const int n    = in_sizes[0] / 256;      // 50000
  const int e    = in_sizes[1] / 2;        // 800000
  const int etot = e + n;

  // workspace layout
  _Float16* XLR16 = (_Float16*)d_ws;                    // n*256 f16
  _Float16* H16   = XLR16 + (size_t)n * 256;            // n*128 f16
  int* col2 = (int*)(H16 + (size_t)n * 128);            // n*CAP
  int* cnt  = col2 + (size_t)n * CAP;                   // n
  int* hist    = cnt + n;                               // 64
  int* cursor  = hist + 64;                             // 64
  int* bcursor = cursor + 64;                           // 256 (196 used)
  int* perm    = bcursor + 256;                         // n
  _Float16* B0h = (_Float16*)(perm + ((n + 3) & ~3));   // 256*256 f16
  _Float16* B1h = B0h + 65536;                          // 256*128 f16
  int* bins = (int*)H16;    // 196*BCAP ints = 4.8 MB, aliases H16 (dead till agg_wave)

  // zero cnt + hist + cursor + bcursor in one shot (contiguous)
  (void)hipMemsetAsync(cnt, 0, ((size_t)n + 384) * sizeof(int), stream);
  convw_kernel<<<96, 256, 0, stream>>>(Wl0, Wr0, Wl1, Wr1, B0h, B1h);

  // fused: pass1 binning (NP blocks, dispatched first) ∥ layer-0 GEMM (NG)
  const int NP = (etot + 2047) / 2048;          // 416 (≡ 0 mod 8)
  const int NG = 2 * ((n + 63) / 64);           // 1564
  gemm_pass1<<<NP + NG, 256, 0, stream>>>(x, B0h, XLR16, n, ei, bins, bcursor,
                                          e, etot, NP);

  const int NB2 = (n + 255) / 256;              // 196
  pass2_kernel<<<NB2, 256, 0, stream>>>(bins, bcursor, cnt, col2, hist, n);
  scatter_kernel<<<(n + 255) / 256, 256, 0, stream>>>(cnt, hist, cursor, perm, n);

  agg_wave<<<(n + 7) / 8, 128, 0, stream>>>(XLR16, col2, cnt, perm, att0, b0, H16, n);
  // layer 1 (A = H16 in f16), 1D grid with XCD-pairing map
  gemm_mfma<<<NG, 256, 0, stream>>>(nullptr, H16, B1h, XLR16, n, 128);
  // layer-1 agg + down proj fused
  agg_down<<<(n + 15) / 16, 256, 0, stream>>>(XLR16, col2, cnt, perm, att1, b1, dW, db, out, n);
}

// Round 13
// 250.564 us; speedup vs baseline: 1.2030x; 1.0802x over previous
//
#include <hip/hip_runtime.h>

#define CAP 64
#define BCAP 6144   // per-bucket edge capacity (mean 4352 + 27 sigma)

typedef _Float16 h8 __attribute__((ext_vector_type(8)));
typedef _Float16 h4 __attribute__((ext_vector_type(4)));
typedef _Float16 h2 __attribute__((ext_vector_type(2)));
typedef float f32x4 __attribute__((ext_vector_type(4)));

__device__ __forceinline__ uint4 pack8(float4 a, float4 b){
  union { h8 h; uint4 u; } cv;
  cv.h = (h8){ (_Float16)a.x, (_Float16)a.y, (_Float16)a.z, (_Float16)a.w,
               (_Float16)b.x, (_Float16)b.y, (_Float16)b.z, (_Float16)b.w };
  return cv.u;
}

// packed-f16 logit partial: sum_k dot2(lrelu(c2k + xr2k), att2k), f32 accum
__device__ __forceinline__ float edge_logit(uint4 xu, const h2* xrh, const h2* avh){
  union { uint4 u; h2 v[4]; } cu; cu.u = xu;
  const h2 z2 = { (_Float16)0.f, (_Float16)0.f };
  const h2 sl = { (_Float16)0.2f, (_Float16)0.2f };
  float p = 0.f;
  #pragma unroll
  for (int k = 0; k < 4; ++k){
    h2 t  = cu.v[k] + xrh[k];
    h2 hi = __builtin_elementwise_max(t, z2);
    h2 lo = __builtin_elementwise_min(t, z2);
    h2 lr = hi + lo * sl;
    p = __builtin_amdgcn_fdot2(lr, avh[k], p, false);
  }
  return p;
}
// accv += w * c (f16 source, f32 accum; fma_mix pattern)
__device__ __forceinline__ void acc_edge(float w, uint4 xu, float* accv){
  union { uint4 u; _Float16 e[8]; } ce; ce.u = xu;
  #pragma unroll
  for (int i = 0; i < 8; ++i) accv[i] += w * (float)ce.e[i];
}

// XCD-pairing tile map: the two column-half blocks (bx=0/1, same by) are
// placed 8 apart in dispatch order -> same XCD residue (round-robin block->XCD)
// and temporally close -> the shared 64KB A-panel stays in that XCD's L2.
// Bijective for any nby (tail handled with rem = nby - (nby & ~7)).
__device__ __forceinline__ void tile_map(int gi, int nby, int& bx, int& by){
  const int nby8 = nby & ~7;
  if (gi < 2 * nby8){
    int g8 = gi >> 4, r = gi & 15;
    bx = r >> 3;
    by = g8 * 8 + (r & 7);
  } else {
    int t = gi - 2 * nby8, rem = nby - nby8;
    bx = t / rem;
    by = nby8 + t % rem;
  }
}

// ---------------- f16 MFMA GEMM body, tile 64 rows x 128 cols ----------------
// 4 waves: wave wx -> cols wx*32..+31 (4x2 MFMA tiles of 16x16x32_f16),
// BK=64, register-prefetch pipeline. LDS rows at exact 128 B with XOR swizzle
// (byte ^= (row&7)<<4): 24576 B total -> 6 blocks/CU. Epilogue restages f16 C
// tile in LDS. A read as f32 (layer 0, fused convert) or f16 (layer 1).
// B read as f32 (layer 0: Wl0 or Wr0 direct, fused convert; pre-offset by
// caller so row index is v*64+srow) or f16 (layer 1: B1h).
__device__ __forceinline__ void gemm_body(
    char* smem, const float* __restrict__ A32, const _Float16* __restrict__ A16,
    const float* __restrict__ B32, const _Float16* __restrict__ Bw,
    _Float16* __restrict__ C, int n, int K, int bx, int by)
{
  char* Abase = smem;            // 64 rows x 128 B (swizzled)
  char* Bbase = smem + 8192;     // 128 rows x 128 B (swizzled)

  const int tid  = threadIdx.x;
  const int lane = tid & 63;
  const int wx   = tid >> 6;
  const int r0   = by * 64;
  const int cb   = bx * 128;
  const int m16  = lane & 15, quad = lane >> 4;

  f32x4 acc[4][2];
  #pragma unroll
  for (int i = 0; i < 4; ++i)
    #pragma unroll
    for (int j = 0; j < 2; ++j)
      acc[i][j] = (f32x4){0.f, 0.f, 0.f, 0.f};

  const int srow = tid >> 2;        // 0..63
  const int kq   = (tid & 3) << 4;  // 0,16,32,48 (elements)
  const int kb   = kq * 2;          // bytes within row
  const int swz  = (srow & 7) << 4; // write-side row swizzle

  uint4 ra[2], rb[2][2];
  const uint4 z = {0u, 0u, 0u, 0u};

  if (r0 + srow < n){
    if (A32){
      const float* p = A32 + (size_t)(r0 + srow) * K + kq;
      ra[0] = pack8(*(const float4*)(p),     *(const float4*)(p + 4));
      ra[1] = pack8(*(const float4*)(p + 8), *(const float4*)(p + 12));
    } else {
      const _Float16* p = A16 + (size_t)(r0 + srow) * K + kq;
      ra[0] = *(const uint4*)(p);
      ra[1] = *(const uint4*)(p + 8);
    }
  } else { ra[0] = z; ra[1] = z; }
  #pragma unroll
  for (int v = 0; v < 2; ++v){
    if (B32){
      const float* p = B32 + (size_t)(v * 64 + srow) * K + kq;
      rb[v][0] = pack8(*(const float4*)(p),     *(const float4*)(p + 4));
      rb[v][1] = pack8(*(const float4*)(p + 8), *(const float4*)(p + 12));
    } else {
      const _Float16* p = Bw + (size_t)(cb + v * 64 + srow) * K + kq;
      rb[v][0] = *(const uint4*)(p);
      rb[v][1] = *(const uint4*)(p + 8);
    }
  }

  const int nt = K >> 6;
  for (int t = 0; t < nt; ++t){
    *(uint4*)(Abase + srow * 128 + (kb ^ swz))        = ra[0];
    *(uint4*)(Abase + srow * 128 + ((kb + 16) ^ swz)) = ra[1];
    #pragma unroll
    for (int v = 0; v < 2; ++v){
      *(uint4*)(Bbase + (v * 64 + srow) * 128 + (kb ^ swz))        = rb[v][0];
      *(uint4*)(Bbase + (v * 64 + srow) * 128 + ((kb + 16) ^ swz)) = rb[v][1];
    }
    __syncthreads();
    if (t + 1 < nt){
      int kt = (t + 1) << 6;
      if (r0 + srow < n){
        if (A32){
          const float* p = A32 + (size_t)(r0 + srow) * K + kt + kq;
          ra[0] = pack8(*(const float4*)(p),     *(const float4*)(p + 4));
          ra[1] = pack8(*(const float4*)(p + 8), *(const float4*)(p + 12));
        } else {
          const _Float16* p = A16 + (size_t)(r0 + srow) * K + kt + kq;
          ra[0] = *(const uint4*)(p);
          ra[1] = *(const uint4*)(p + 8);
        }
      }
      #pragma unroll
      for (int v = 0; v < 2; ++v){
        if (B32){
          const float* p = B32 + (size_t)(v * 64 + srow) * K + kt + kq;
          rb[v][0] = pack8(*(const float4*)(p),     *(const float4*)(p + 4));
          rb[v][1] = pack8(*(const float4*)(p + 8), *(const float4*)(p + 12));
        } else {
          const _Float16* p = Bw + (size_t)(cb + v * 64 + srow) * K + kt + kq;
          rb[v][0] = *(const uint4*)(p);
          rb[v][1] = *(const uint4*)(p + 8);
        }
      }
    }
    const int swr = (m16 & 7) << 4;   // read-side row swizzle
    #pragma unroll
    for (int ks = 0; ks < 2; ++ks){
      const int k0 = ks * 32 + quad * 8;
      const int cbyte = (k0 * 2) ^ swr;
      h8 a[4], b[2];
      #pragma unroll
      for (int i = 0; i < 4; ++i)
        a[i] = *(const h8*)(Abase + (i * 16 + m16) * 128 + cbyte);
      #pragma unroll
      for (int j = 0; j < 2; ++j)
        b[j] = *(const h8*)(Bbase + (wx * 32 + j * 16 + m16) * 128 + cbyte);
      #pragma unroll
      for (int i = 0; i < 4; ++i)
        #pragma unroll
        for (int j = 0; j < 2; ++j)
          acc[i][j] = __builtin_amdgcn_mfma_f32_16x16x32_f16(a[i], b[j], acc[i][j], 0, 0, 0);
    }
    __syncthreads();
  }

  _Float16* Csm = (_Float16*)smem;
  #pragma unroll
  for (int i = 0; i < 4; ++i)
    #pragma unroll
    for (int r = 0; r < 4; ++r){
      int lrow = i * 16 + quad * 4 + r;
      _Float16* cp = Csm + lrow * 136 + wx * 32 + m16;
      #pragma unroll
      for (int j = 0; j < 2; ++j)
        cp[j * 16] = (_Float16)acc[i][j][r];
    }
  __syncthreads();
  #pragma unroll
  for (int v = 0; v < 4; ++v){
    int idx = v * 256 + tid;            // 1024 chunks of 8 f16
    int row = idx >> 4, cx = (idx & 15) * 8;
    if (r0 + row < n)
      *(uint4*)(C + (size_t)(r0 + row) * 256 + cb + cx)
        = *(const uint4*)(Csm + row * 136 + cx);
  }
}

// standalone GEMM (layer 1), 1D grid with XCD-pairing tile map
__global__ __launch_bounds__(256) void gemm_mfma(
    const _Float16* __restrict__ A16, const _Float16* __restrict__ Bw,
    _Float16* __restrict__ C, int n, int K)
{
  __shared__ __align__(16) char smem[24576];
  const int nby = (n + 63) / 64;
  int bx, by;
  tile_map(blockIdx.x, nby, bx, by);
  gemm_body(smem, nullptr, A16, nullptr, Bw, C, n, K, bx, by);
}

// ---------------- fused: layer-0 GEMM ∥ edge binning ∥ B1h pack --------------
// Block regions: [0,NP) binning; [NP,NP+32) B1h f32->f16 pack (consumed by
// gemm_mfma two launches later -- no race); [NP+32,..) layer-0 GEMM with
// XCD-pairing map (NP+32 = 448 ≡ 0 mod 8 keeps residue alignment). gemm0's B
// is read DIRECTLY from Wl0/Wr0 f32 (block bx=0 -> Wl0, bx=1 -> Wr0; 512 KB
// total, L2-resident) with the same fused convert as A -- convw_kernel and
// B0h are deleted.
__global__ __launch_bounds__(256) void gemm_pass1(
    const float* __restrict__ A32,
    const float* __restrict__ Wl0, const float* __restrict__ Wr0,
    const float* __restrict__ Wl1, const float* __restrict__ Wr1,
    _Float16* __restrict__ B1h, _Float16* __restrict__ C, int n,
    const int* __restrict__ ei, int* __restrict__ bins, int* __restrict__ bcursor,
    int e_orig, int etot, int NP)
{
  __shared__ __align__(16) char smem[24576];
  const int lin = blockIdx.x;
  if (lin >= NP + 32){
    const int nby = (n + 63) / 64;
    int bx, by;
    tile_map(lin - NP - 32, nby, bx, by);
    gemm_body(smem, A32, nullptr, (bx == 0) ? Wl0 : Wr0, nullptr, C, n, 256, bx, by);
  } else if (lin >= NP){
    int t = (lin - NP) * 256 + (int)threadIdx.x;   // 0..8191 float4 units
    const float* s; _Float16* d; int off;
    if (t < 4096){ s = Wl1; d = B1h;         off = t; }
    else         { s = Wr1; d = B1h + 16384; off = t - 4096; }
    float4 f = ((const float4*)s)[off];
    h4 h = { (_Float16)f.x, (_Float16)f.y, (_Float16)f.z, (_Float16)f.w };
    *(h4*)(d + 4 * (size_t)off) = h;
  } else {
    int* lcnt  = (int*)smem;                 // 196
    int* gbase = lcnt + 256;                 // 196
    const int tid = threadIdx.x;
    if (tid < 196) lcnt[tid] = 0;
    __syncthreads();
    const int base = lin * 2048 + tid;
    int pk[8], bk[8], lp[8];
    #pragma unroll
    for (int k = 0; k < 8; ++k){
      int i = base + k * 256;
      bk[k] = -1;
      if (i < etot){
        int src, dst;
        if (i < e_orig){ src = ei[i]; dst = ei[e_orig + i]; }
        else { src = i - e_orig; dst = src; }           // self loops
        bk[k] = dst >> 8;
        pk[k] = ((dst & 255) << 24) | src;              // src < 2^24
      }
    }
    #pragma unroll
    for (int k = 0; k < 8; ++k)
      if (bk[k] >= 0) lp[k] = atomicAdd(&lcnt[bk[k]], 1);
    __syncthreads();
    if (tid < 196 && lcnt[tid] > 0)
      gbase[tid] = atomicAdd(&bcursor[tid], lcnt[tid]);
    __syncthreads();
    #pragma unroll
    for (int k = 0; k < 8; ++k)
      if (bk[k] >= 0){
        int p = gbase[bk[k]] + lp[k];
        if (p < BCAP) bins[(size_t)bk[k] * BCAP + p] = pk[k];
      }
  }
}

// ---------------- pass 2: adjacency materialization + LOCAL degree sort ------
// Block b owns nodes [b*256, b*256+256). col2 staged in LDS (64 KB) via LDS
// atomics, written out coalesced. Additionally a bucket-local counting sort
// by descending clamped degree emits perm[b*256 + rank] = node (holes = -1 in
// the tail bucket). Degrees are iid across buckets, so bucket-local sorting
// gives the same within-wave balance as the old global sort -- hist_kernel
// and scatter_kernel are deleted (2 launches + gaps).
__global__ __launch_bounds__(256) void pass2_kernel(
    const int* __restrict__ bins, const int* __restrict__ bcursor,
    int* __restrict__ cnt, int* __restrict__ col2, int* __restrict__ perm, int n)
{
  __shared__ int stage[256 * CAP];   // 64 KB
  __shared__ int lcnt2[256];
  __shared__ int dh[64], dbase[64], dcur[64];
  const int b = blockIdx.x, tid = threadIdx.x;
  lcnt2[tid] = 0;
  if (tid < 64){ dh[tid] = 0; dcur[tid] = 0; }
  __syncthreads();
  int ecnt = bcursor[b]; if (ecnt > BCAP) ecnt = BCAP;
  for (int i = tid; i < ecnt; i += 256){
    int v = bins[(size_t)b * BCAP + i];
    int src = v & 0xFFFFFF;
    int loc = ((unsigned)v) >> 24;
    int pos = atomicAdd(&lcnt2[loc], 1);
    if (pos < CAP) stage[loc * CAP + pos] = src;
  }
  perm[b * 256 + tid] = -1;
  __syncthreads();
  const int node = b * 256 + tid;
  int dc = 1;
  if (node < n){
    int d = lcnt2[tid];
    cnt[node] = d;
    dc = d < 1 ? 1 : (d > CAP ? CAP : d);
    atomicAdd(&dh[dc - 1], 1);
  }
  __syncthreads();
  if (tid == 0){
    int acc = 0;
    for (int k = 63; k >= 0; --k){ dbase[k] = acc; acc += dh[k]; }  // descending
  }
  __syncthreads();
  if (node < n){
    int rank = dbase[dc - 1] + atomicAdd(&dcur[dc - 1], 1);
    perm[b * 256 + rank] = node;
  }
  // col2 writeout (stage/lcnt2 stable since first barrier)
  const uint4* sg = (const uint4*)stage;
  uint4* c4 = (uint4*)col2;
  for (int k2 = tid; k2 < 4096; k2 += 256){       // 4096 uint4 = 64 KB
    int nd = b * 256 + (k2 >> 4);
    if (nd < n) c4[(size_t)nd * 16 + (k2 & 15)] = sg[k2];
  }
}

// ---------------- GATv2 aggregation: 16-lane group per node, 8 ch/lane -------
// Bucket-local degree-sorted perm (balanced waves) + 4-edge unroll + depth-8
// rotating prefetch. VALU diet: LDS edge-index table, packed-f16 logit via
// v_pk + v_dot2_f32_f16, fma_mix accumulate.
__global__ __launch_bounds__(128) void agg_wave(
    const _Float16* __restrict__ XLR, const int* __restrict__ col2,
    const int* __restrict__ cnt, const int* __restrict__ perm,
    const float* __restrict__ att,
    const float* __restrict__ bias, _Float16* __restrict__ H16, int nslot)
{
  __shared__ int idxs[8][72];
  const int lane  = threadIdx.x & 63;
  const int g     = lane >> 4;          // group within wave (0..3)
  const int ll    = lane & 15;
  const int gbase = g << 4;
  const int nl    = ((threadIdx.x >> 6) << 2) + g;   // 0..7
  const int slot  = blockIdx.x * 8 + nl;
  if (slot >= nslot) return;
  const int node = perm[slot];
  if (node < 0) return;                 // hole (tail bucket), group-uniform
  int deg = cnt[node]; if (deg > CAP) deg = CAP;
  const int c0 = 8 * ll;

  h2 xrh[4], avh[4];
  {
    union { uint4 u; h2 v[4]; } xc;
    xc.u = *(const uint4*)(XLR + (size_t)node * 256 + 128 + c0);
    #pragma unroll
    for (int k = 0; k < 4; ++k) xrh[k] = xc.v[k];
    #pragma unroll
    for (int k = 0; k < 4; ++k)
      avh[k] = (h2){ (_Float16)att[c0 + 2*k], (_Float16)att[c0 + 2*k + 1] };
  }

  // stage edge indices: [0,deg) real, [deg,72) clamped to edge 0 (deg>=1)
  {
    int sq[4];
    #pragma unroll
    for (int q = 0; q < 4; ++q)
      sq[q] = (ll + 16*q < deg) ? col2[(size_t)node * CAP + ll + 16*q] : 0;
    int s0 = __shfl(sq[0], gbase);
    #pragma unroll
    for (int q = 0; q < 4; ++q)
      idxs[nl][ll + 16*q] = (ll + 16*q < deg) ? sq[q] : s0;
    if (ll < 8) idxs[nl][64 + ll] = s0;
  }
  const int* idxp = idxs[nl];

  float l = 0.f, accv[8];
  #pragma unroll
  for (int i = 0; i < 8; ++i) accv[i] = 0.f;

  uint4 x0, x1, x2, x3, x4, x5, x6, x7;
  {
    int e0 = idxp[0], e1 = idxp[1], e2 = idxp[2], e3 = idxp[3];
    int e4 = idxp[4], e5 = idxp[5], e6 = idxp[6], e7 = idxp[7];
    x0 = *(const uint4*)(XLR + (size_t)e0 * 256 + c0);
    x1 = *(const uint4*)(XLR + (size_t)e1 * 256 + c0);
    x2 = *(const uint4*)(XLR + (size_t)e2 * 256 + c0);
    x3 = *(const uint4*)(XLR + (size_t)e3 * 256 + c0);
    x4 = *(const uint4*)(XLR + (size_t)e4 * 256 + c0);
    x5 = *(const uint4*)(XLR + (size_t)e5 * 256 + c0);
    x6 = *(const uint4*)(XLR + (size_t)e6 * 256 + c0);
    x7 = *(const uint4*)(XLR + (size_t)e7 * 256 + c0);
  }

  int j = 0;
  for (; j + 4 <= deg; j += 4){
    uint4 y0 = x0, y1 = x1, y2 = x2, y3 = x3;
    x0 = x4; x1 = x5; x2 = x6; x3 = x7;
    int e8  = idxp[j + 8],  e9  = idxp[j + 9];
    int e10 = idxp[j + 10], e11 = idxp[j + 11];
    x4 = *(const uint4*)(XLR + (size_t)e8  * 256 + c0);
    x5 = *(const uint4*)(XLR + (size_t)e9  * 256 + c0);
    x6 = *(const uint4*)(XLR + (size_t)e10 * 256 + c0);
    x7 = *(const uint4*)(XLR + (size_t)e11 * 256 + c0);
    float p0 = edge_logit(y0, xrh, avh);
    float p1 = edge_logit(y1, xrh, avh);
    float p2 = edge_logit(y2, xrh, avh);
    float p3 = edge_logit(y3, xrh, avh);
    p0 += __shfl_xor(p0, 1);  p1 += __shfl_xor(p1, 1);
    p2 += __shfl_xor(p2, 1);  p3 += __shfl_xor(p3, 1);
    p0 += __shfl_xor(p0, 2);  p1 += __shfl_xor(p1, 2);
    p2 += __shfl_xor(p2, 2);  p3 += __shfl_xor(p3, 2);
    float w0 = __expf(p0), w1 = __expf(p1), w2 = __expf(p2), w3 = __expf(p3);
    l += (w0 + w1) + (w2 + w3);
    acc_edge(w0, y0, accv); acc_edge(w1, y1, accv);
    acc_edge(w2, y2, accv); acc_edge(w3, y3, accv);
  }
  // tail: up to 3 edges, already resident in x0..x2
  #pragma unroll
  for (int r = 0; r < 3; ++r){
    if (j + r < deg){
      uint4 xe = (r == 0) ? x0 : ((r == 1) ? x1 : x2);
      float p = edge_logit(xe, xrh, avh);
      p += __shfl_xor(p, 1);
      p += __shfl_xor(p, 2);
      float w = __expf(p);
      l += w;
      acc_edge(w, xe, accv);
    }
  }
  float inv = 1.f / l;
  union { h8 h; uint4 u; } o;
  #pragma unroll
  for (int i = 0; i < 8; ++i)
    o.h[i] = (_Float16)(accv[i] * inv + bias[c0 + i]);
  *(uint4*)(H16 + (size_t)node * 128 + c0) = o.u;
}

// ---------------- layer-1 aggregation fused with down_proj -------------------
// Same VALU-diet pipeline; h staged f32 in LDS; then each thread computes
// 2 (node, o) dot products against LDS-staged dW. Holes guarded (no early
// return: __syncthreads).
__global__ __launch_bounds__(256) void agg_down(
    const _Float16* __restrict__ XLR, const int* __restrict__ col2,
    const int* __restrict__ cnt, const int* __restrict__ perm,
    const float* __restrict__ att,
    const float* __restrict__ bias, const float* __restrict__ dW,
    const float* __restrict__ db, float* __restrict__ out, int nslot)
{
  __shared__ float dwb[32][129];
  __shared__ float hsm[16][128];
  __shared__ int idxs[16][72];
  for (int i = threadIdx.x; i < 32 * 128; i += 256)
    dwb[i >> 7][i & 127] = dW[i];

  const int lane  = threadIdx.x & 63;
  const int g     = lane >> 4;
  const int ll    = lane & 15;
  const int gbase = g << 4;
  const int nl    = ((threadIdx.x >> 6) << 2) + g;   // 0..15
  const int slot  = blockIdx.x * 16 + nl;
  int node = (slot < nslot) ? perm[slot] : -1;
  const bool valid = node >= 0;
  node = valid ? node : 0;
  int deg = 0;
  if (valid){ deg = cnt[node]; if (deg > CAP) deg = CAP; }
  const int c0 = 8 * ll;

  h2 xrh[4], avh[4];
  {
    union { uint4 u; h2 v[4]; } xc;
    xc.u = (uint4){0u,0u,0u,0u};
    if (valid) xc.u = *(const uint4*)(XLR + (size_t)node * 256 + 128 + c0);
    #pragma unroll
    for (int k = 0; k < 4; ++k) xrh[k] = xc.v[k];
    #pragma unroll
    for (int k = 0; k < 4; ++k)
      avh[k] = (h2){ (_Float16)att[c0 + 2*k], (_Float16)att[c0 + 2*k + 1] };
  }

  {
    int sq[4];
    #pragma unroll
    for (int q = 0; q < 4; ++q)
      sq[q] = (valid && ll + 16*q < deg) ? col2[(size_t)node * CAP + ll + 16*q] : 0;
    int s0 = __shfl(sq[0], gbase);
    #pragma unroll
    for (int q = 0; q < 4; ++q)
      idxs[nl][ll + 16*q] = (ll + 16*q < deg) ? sq[q] : s0;
    if (ll < 8) idxs[nl][64 + ll] = s0;
  }
  const int* idxp = idxs[nl];

  float l = 0.f, accv[8];
  #pragma unroll
  for (int i = 0; i < 8; ++i) accv[i] = 0.f;

  uint4 x0, x1, x2, x3, x4, x5, x6, x7;
  {
    int e0 = idxp[0], e1 = idxp[1], e2 = idxp[2], e3 = idxp[3];
    int e4 = idxp[4], e5 = idxp[5], e6 = idxp[6], e7 = idxp[7];
    x0 = *(const uint4*)(XLR + (size_t)e0 * 256 + c0);
    x1 = *(const uint4*)(XLR + (size_t)e1 * 256 + c0);
    x2 = *(const uint4*)(XLR + (size_t)e2 * 256 + c0);
    x3 = *(const uint4*)(XLR + (size_t)e3 * 256 + c0);
    x4 = *(const uint4*)(XLR + (size_t)e4 * 256 + c0);
    x5 = *(const uint4*)(XLR + (size_t)e5 * 256 + c0);
    x6 = *(const uint4*)(XLR + (size_t)e6 * 256 + c0);
    x7 = *(const uint4*)(XLR + (size_t)e7 * 256 + c0);
  }

  int j = 0;
  for (; j + 4 <= deg; j += 4){
    uint4 y0 = x0, y1 = x1, y2 = x2, y3 = x3;
    x0 = x4; x1 = x5; x2 = x6; x3 = x7;
    int e8  = idxp[j + 8],  e9  = idxp[j + 9];
    int e10 = idxp[j + 10], e11 = idxp[j + 11];
    x4 = *(const uint4*)(XLR + (size_t)e8  * 256 + c0);
    x5 = *(const uint4*)(XLR + (size_t)e9  * 256 + c0);
    x6 = *(const uint4*)(XLR + (size_t)e10 * 256 + c0);
    x7 = *(const uint4*)(XLR + (size_t)e11 * 256 + c0);
    float p0 = edge_logit(y0, xrh, avh);
    float p1 = edge_logit(y1, xrh, avh);
    float p2 = edge_logit(y2, xrh, avh);
    float p3 = edge_logit(y3, xrh, avh);
    p0 += __shfl_xor(p0, 1);  p1 += __shfl_xor(p1, 1);
    p2 += __shfl_xor(p2, 1);  p3 += __shfl_xor(p3, 1);
    p0 += __shfl_xor(p0, 2);  p1 += __shfl_xor(p1, 2);
    p2 += __shfl_xor(p2, 2);  p3 += __shfl_xor(p3, 2);
    float w0 = __expf(p0), w1 = __expf(p1), w2 = __expf(p2), w3 = __expf(p3);
    l += (w0 + w1) + (w2 + w3);
    acc_edge(w0, y0, accv); acc_edge(w1, y1, accv);
    acc_edge(w2, y2, accv); acc_edge(w3, y3, accv);
  }
  #pragma unroll
  for (int r = 0; r < 3; ++r){
    if (j + r < deg){
      uint4 xe = (r == 0) ? x0 : ((r == 1) ? x1 : x2);
      float p = edge_logit(xe, xrh, avh);
      p += __shfl_xor(p, 1);
      p += __shfl_xor(p, 2);
      float w = __expf(p);
      l += w;
      acc_edge(w, xe, accv);
    }
  }
  {
    float inv = (deg > 0) ? 1.f / l : 0.f;
    #pragma unroll
    for (int i = 0; i < 8; ++i)
      hsm[nl][c0 + i] = accv[i] * inv + bias[c0 + i];
  }
  __syncthreads();

  // ---- down phase: 512 outputs over 256 threads (2 each) ----
  const int o = threadIdx.x & 31;
  #pragma unroll
  for (int h2i = 0; h2i < 2; ++h2i){
    int nl2 = (threadIdx.x >> 5) + h2i * 8;
    int slot2 = blockIdx.x * 16 + nl2;
    int n2 = (slot2 < nslot) ? perm[slot2] : -1;
    float sum = 0.f;
    #pragma unroll 8
    for (int k = 0; k < 128; ++k)
      sum += hsm[nl2][k] * dwb[o][k];
    if (n2 >= 0)
      out[(size_t)n2 * 32 + o] = sum + db[o];
  }
}

extern "C" void kernel_launch(void* const* d_in, const int* in_sizes, int n_in,
                              void* d_out, int out_size, void* d_ws, size_t ws_size,
                              hipStream_t stream) {
  const float* x     = (const float*)d_in[0];
  const int*   ei    = (const int*)  d_in[1];
  const float* Wl0   = (const float*)d_in[2];
  const float* Wr0   = (const float*)d_in[3];
  const float* att0  = (const float*)d_in[4];
  const float* b0    = (const float*)d_in[5];
  const float* Wl1   = (const float*)d_in[6];
  const float* Wr1   = (const float*)d_in[7];
  const float* att1  = (const float*)d_in[8];
  const float* b1    = (const float*)d_in[9];
  const float* dW    = (const float*)d_in[10];
  const float* db    = (const float*)d_in[11];
  float* out = (float*)d_out;

  const int n    = in_sizes[0] / 256;      // 50000
  const int e    = in_sizes[1] / 2;        // 800000
  const int etot = e + n;

  const int NB2   = (n + 255) / 256;       // 196 buckets
  const int NSLOT = NB2 * 256;             // 50176 slots (holes = -1)

  // workspace layout
  _Float16* XLR16 = (_Float16*)d_ws;                    // n*256 f16
  _Float16* H16   = XLR16 + (size_t)n * 256;            // n*128 f16
  int* col2 = (int*)(H16 + (size_t)n * 128);            // n*CAP
  int* cnt  = col2 + (size_t)n * CAP;                   // n
  int* bcursor = cnt + n;                               // 256 (196 used)
  int* perm    = bcursor + 256;                         // NSLOT
  _Float16* B1h = (_Float16*)(perm + NSLOT);            // 256*128 f16
  int* bins = (int*)H16;    // 196*BCAP ints = 4.8 MB, aliases H16 (dead till agg_wave)

  (void)hipMemsetAsync(bcursor, 0, 256 * sizeof(int), stream);

  // fused: binning (NP) + B1h pack (32) + layer-0 GEMM (NG, XCD-pairing map)
  const int NP = (etot + 2047) / 2048;          // 416 (NP+32 = 448 ≡ 0 mod 8)
  const int NG = 2 * ((n + 63) / 64);           // 1564
  gemm_pass1<<<NP + 32 + NG, 256, 0, stream>>>(x, Wl0, Wr0, Wl1, Wr1, B1h,
                                               XLR16, n, ei, bins, bcursor,
                                               e, etot, NP);

  // pass2: adjacency + cnt + bucket-local degree sort (perm)
  pass2_kernel<<<NB2, 256, 0, stream>>>(bins, bcursor, cnt, col2, perm, n);

  agg_wave<<<NSLOT / 8, 128, 0, stream>>>(XLR16, col2, cnt, perm, att0, b0, H16, NSLOT);
  // layer 1 (A = H16 in f16), 1D grid with XCD-pairing map
  gemm_mfma<<<NG, 256, 0, stream>>>(H16, B1h, XLR16, n, 128);
  // layer-1 agg + down proj fused
  agg_down<<<NSLOT / 16, 256, 0, stream>>>(XLR16, col2, cnt, perm, att1, b1,
                                           dW, db, out, NSLOT);
}